// Round 5
// baseline (820.914 us; speedup 1.0000x reference)
//
#include <hip/hip_runtime.h>
#include <math.h>

#define N_NODES 131072
#define N_DST   16384
#define DEG     16
#define HID     256
#define N_EDGES 262144

typedef __bf16 bf16_8 __attribute__((ext_vector_type(8)));
typedef float  f32_4  __attribute__((ext_vector_type(4)));

// tanh-approx gelu via hardware v_exp_f32: |err| <~1e-3, threshold is 2.2e-2
__device__ __forceinline__ float gelu_f(float v) {
    float t = 1.5957691216f * fmaf(v * v, 0.044715f * v, v);  // 2*c0*(v+0.044715v^3)
    return v / (1.0f + __expf(-t));
}
__device__ __forceinline__ f32_4 zero4() {
    f32_4 z; z[0] = 0.f; z[1] = 0.f; z[2] = 0.f; z[3] = 0.f; return z;
}

// async global->LDS, 16B per lane. LDS side must be wave-uniform base + lane*16.
__device__ __forceinline__ void load_lds16(const __bf16* g, __bf16* l) {
    __builtin_amdgcn_global_load_lds(
        (__attribute__((address_space(1))) void*)g,
        (__attribute__((address_space(3))) void*)l, 16, 0, 0);
}

// ---------------- prep: fp32 -> bf16 weights ----------------
__global__ void prep_kernel(__bf16* __restrict__ out,
                            const float* __restrict__ w2,
                            const float* __restrict__ w3,
                            const float* __restrict__ mw1,
                            const float* __restrict__ mw2,
                            const float* __restrict__ mw3) {
    int stride = gridDim.x * blockDim.x;
    for (int i = blockIdx.x * blockDim.x + threadIdx.x; i < 589824; i += stride) {
        float v;
        if      (i <  65536) v = w2[i];
        else if (i < 131072) v = w3[i - 65536];
        else if (i < 393216) v = mw1[i - 131072];
        else if (i < 524288) v = mw2[i - 393216];
        else                 v = mw3[i - 524288];
        out[i] = (__bf16)v;
    }
}

// ---------------- encoder layer 1 (K=3): weights in registers, grid-stride ----
__global__ __launch_bounds__(256) void enc1_kernel(
    const float* __restrict__ x, const float* __restrict__ w1,
    const float* __restrict__ b1, __bf16* __restrict__ h1) {
    const int c8   = threadIdx.x & 31;
    const int nloc = threadIdx.x >> 5;
    float w[24], bb[8];
    #pragma unroll
    for (int i = 0; i < 6; i++) *(float4*)&w[i * 4] = ((const float4*)w1)[c8 * 6 + i];
    *(float4*)&bb[0] = ((const float4*)b1)[c8 * 2 + 0];
    *(float4*)&bb[4] = ((const float4*)b1)[c8 * 2 + 1];
    for (int n = blockIdx.x * 8 + nloc; n < N_NODES; n += gridDim.x * 8) {
        float x0 = x[n * 3 + 0], x1 = x[n * 3 + 1], x2 = x[n * 3 + 2];
        bf16_8 o;
        #pragma unroll
        for (int j = 0; j < 8; j++) {
            float v = fmaf(x2, w[j * 3 + 2],
                      fmaf(x1, w[j * 3 + 1],
                      fmaf(x0, w[j * 3 + 0], bb[j])));
            o[j] = (__bf16)gelu_f(v);
        }
        *(bf16_8*)&h1[(size_t)n * 256 + c8 * 8] = o;
    }
}

// ---------------- mgemm (R3 config): C = gelu(A @ W^T + b), K=512 GEMMs ----
// 256 threads = 4 waves (2x2), block tile 128x128, wave tile 64x64, BK=64.
template<int K, bool GATHER>
__global__ __launch_bounds__(256, 3) void mgemm(
    const __bf16* __restrict__ Ag, const __bf16* __restrict__ h,
    const int* __restrict__ edges, const __bf16* __restrict__ W,
    const float* __restrict__ bias, __bf16* __restrict__ Cb,
    int NB, int Nfull, int e0)
{
    __shared__ __align__(16) __bf16 sA[128 * 64];
    __shared__ __align__(16) __bf16 sB[128 * 64];
    __shared__ int s_src[128];
    __shared__ int s_dst[128];

    const int tid  = threadIdx.x;
    const int mblk = blockIdx.x / NB;
    const int nblk = blockIdx.x % NB;
    const int m0 = mblk * 128, n0 = nblk * 128;
    const int wave = tid >> 6, lane = tid & 63, ln = lane & 15, quad = lane >> 4;
    const int wm = wave >> 1, wn = wave & 1;

    if (GATHER && tid < 128) {
        int e = e0 + m0 + tid;
        s_src[tid] = edges[2 * e + 1];
        s_dst[tid] = edges[2 * e + 0];
    }

    f32_4 acc[4][4];
    #pragma unroll
    for (int i = 0; i < 4; i++)
        #pragma unroll
        for (int j = 0; j < 4; j++) acc[i][j] = zero4();

    for (int kb = 0; kb < K / 64; kb++) {
        __syncthreads();
        #pragma unroll
        for (int i = 0; i < 4; i++) {
            int idx = i * 256 + tid;
            int row = idx >> 3, kgs = idx & 7;
            int kg  = kgs ^ (row & 7);
            const __bf16* gsrc;
            if (GATHER) {
                int col  = kb * 64 + kg * 8;
                int node = (col < 256) ? s_src[row] : s_dst[row];
                gsrc = h + (size_t)node * HID + (col & 255);
            } else {
                gsrc = Ag + (size_t)(m0 + row) * K + kb * 64 + kg * 8;
            }
            load_lds16(gsrc, &sA[idx * 8]);
            const __bf16* gw = W + (size_t)(n0 + row) * K + kb * 64 + kg * 8;
            load_lds16(gw, &sB[idx * 8]);
        }
        __syncthreads();
        #pragma unroll
        for (int ks = 0; ks < 2; ks++) {
            bf16_8 af[4], bfr[4];
            int kg = ks * 4 + quad;
            #pragma unroll
            for (int mt = 0; mt < 4; mt++) {
                int mr = wm * 64 + mt * 16 + ln;
                af[mt] = *(const bf16_8*)&sA[mr * 64 + (kg ^ (mr & 7)) * 8];
            }
            #pragma unroll
            for (int nt = 0; nt < 4; nt++) {
                int nr = wn * 64 + nt * 16 + ln;
                bfr[nt] = *(const bf16_8*)&sB[nr * 64 + (kg ^ (nr & 7)) * 8];
            }
            #pragma unroll
            for (int mt = 0; mt < 4; mt++)
                #pragma unroll
                for (int nt = 0; nt < 4; nt++)
                    acc[mt][nt] = __builtin_amdgcn_mfma_f32_16x16x32_bf16(af[mt], bfr[nt], acc[mt][nt], 0, 0, 0);
        }
    }

    // epilogue: bias + gelu, LDS-transpose for coalesced 16B stores
    __syncthreads();
    __bf16* sw = ((wave & 2) ? sB : sA) + (wave & 1) * 4096;
    #pragma unroll
    for (int nt = 0; nt < 4; nt++) {
        int col = n0 + wn * 64 + nt * 16 + ln;
        float bb = bias[col];
        #pragma unroll
        for (int mt = 0; mt < 4; mt++) {
            #pragma unroll
            for (int r = 0; r < 4; r++) {
                int rowL = mt * 16 + quad * 4 + r;
                float v = gelu_f(acc[mt][nt][r] + bb);
                int colL = nt * 16 + ln;
                sw[rowL * 64 + ((colL + rowL * 8) & 63)] = (__bf16)v;
            }
        }
    }
    __syncthreads();
    #pragma unroll
    for (int p = 0; p < 8; p++) {
        int rowL = p * 8 + (lane >> 3);
        int c8 = lane & 7;
        bf16_8 vv = *(const bf16_8*)&sw[rowL * 64 + ((c8 * 8 + rowL * 8) & 63)];
        int rowE = m0 + wm * 64 + rowL;
        *(bf16_8*)&Cb[(size_t)rowE * Nfull + n0 + wn * 64 + c8 * 8] = vv;
    }
}

// ---------------- rgemm: K=256,N=256 GEMM with register-resident B ----
// 4 waves; wave w owns cols [w*64, w*64+64): full W quarter in 128 VGPRs.
// Grid-stride over 64-row m-tiles; per tile: stage A 32KB -> 32 ds_read + 128 MFMA/wave.
template<bool POOL, bool FOURIER, bool GELU>
__global__ __launch_bounds__(256, 2) void rgemm(
    const __bf16* __restrict__ A, const __bf16* __restrict__ W,
    const float* __restrict__ bias, __bf16* __restrict__ Cb,
    float* __restrict__ Cf, const float* __restrict__ pos,
    const float* __restrict__ bfour, const int* __restrict__ edges,
    int Mtiles, int e0)
{
    __shared__ __align__(16) __bf16 sA[64 * 256];               // 32 KB
    __shared__ __align__(16) __bf16 sEpi[POOL ? 1 : 4][4096];   // 8 / 32 KB

    const int tid  = threadIdx.x;
    const int wave = tid >> 6, lane = tid & 63, ln = lane & 15, quad = lane >> 4;

    // B quarter -> registers (once per block)
    bf16_8 breg[8][4];
    float bb[4], Bc0[4], Bc1[4];
    #pragma unroll
    for (int nt = 0; nt < 4; nt++) {
        int col = wave * 64 + nt * 16 + ln;
        bb[nt] = bias[col];
        if (FOURIER) {
            int jm = col & 127;
            Bc0[nt] = bfour[jm * 2 + 0];
            Bc1[nt] = bfour[jm * 2 + 1];
        }
        #pragma unroll
        for (int ks = 0; ks < 8; ks++)
            breg[ks][nt] = *(const bf16_8*)&W[(size_t)col * 256 + ks * 32 + quad * 8];
    }
    const bool iscos = FOURIER && (wave < 2);  // cols<128 <=> wave 0/1 (wave-uniform)

    for (int t = blockIdx.x; t < Mtiles; t += gridDim.x) {
        const int m0 = t * 64;
        __syncthreads();  // protect sA from previous iteration's readers
        #pragma unroll
        for (int i = 0; i < 8; i++) {
            int idx = i * 256 + tid;             // 0..2047
            int row = idx >> 5, kgs = idx & 31;
            int kg  = kgs ^ (row & 7);
            load_lds16(&A[(size_t)(m0 + row) * 256 + kg * 8], &sA[idx * 8]);
        }
        __syncthreads();  // drains DMA

        f32_4 acc[4][4];
        #pragma unroll
        for (int i = 0; i < 4; i++)
            #pragma unroll
            for (int j = 0; j < 4; j++) acc[i][j] = zero4();

        #pragma unroll
        for (int ks = 0; ks < 8; ks++) {
            int kg = ks * 4 + quad;
            bf16_8 af[4];
            #pragma unroll
            for (int mt = 0; mt < 4; mt++) {
                int mr = mt * 16 + ln;
                af[mt] = *(const bf16_8*)&sA[mr * 256 + (kg ^ (ln & 7)) * 8];
            }
            #pragma unroll
            for (int mt = 0; mt < 4; mt++)
                #pragma unroll
                for (int nt = 0; nt < 4; nt++)
                    acc[mt][nt] = __builtin_amdgcn_mfma_f32_16x16x32_bf16(af[mt], breg[ks][nt], acc[mt][nt], 0, 0, 0);
        }

        if (POOL) {
            #pragma unroll
            for (int nt = 0; nt < 4; nt++) {
                #pragma unroll
                for (int mt = 0; mt < 4; mt++) {
                    float s = acc[mt][nt][0] + acc[mt][nt][1] + acc[mt][nt][2] + acc[mt][nt][3];
                    s += __shfl_xor(s, 16);
                    s += __shfl_xor(s, 32);
                    if (quad == 0) {
                        int dst = edges[2 * (e0 + m0 + mt * 16)];
                        Cf[(size_t)dst * HID + wave * 64 + nt * 16 + ln] = s * 0.0625f + bb[nt];
                    }
                }
            }
        } else {
            // wave-private LDS transpose -> 16B coalesced stores (no barrier needed)
            __bf16* sw = sEpi[POOL ? 0 : wave];
            #pragma unroll
            for (int nt = 0; nt < 4; nt++) {
                #pragma unroll
                for (int mt = 0; mt < 4; mt++) {
                    #pragma unroll
                    for (int r = 0; r < 4; r++) {
                        int rowL = mt * 16 + quad * 4 + r;
                        float v = acc[mt][nt][r] + bb[nt];
                        if (GELU) v = gelu_f(v);
                        if (FOURIER) {
                            int rowE = m0 + rowL;
                            float f = 6.2831853071795864f *
                                      fmaf(pos[rowE * 2 + 1], Bc1[nt], pos[rowE * 2 + 0] * Bc0[nt]);
                            v += iscos ? __cosf(f) : __sinf(f);
                        }
                        int colL = nt * 16 + ln;
                        sw[rowL * 64 + ((colL + rowL * 8) & 63)] = (__bf16)v;
                    }
                }
            }
            #pragma unroll
            for (int p = 0; p < 8; p++) {
                int rowL = p * 8 + (lane >> 3);
                int c8 = lane & 7;
                bf16_8 vv = *(const bf16_8*)&sw[rowL * 64 + ((c8 * 8 + rowL * 8) & 63)];
                *(bf16_8*)&Cb[(size_t)(m0 + rowL) * 256 + wave * 64 + c8 * 8] = vv;
            }
        }
    }
}

extern "C" void kernel_launch(void* const* d_in, const int* in_sizes, int n_in,
                              void* d_out, int out_size, void* d_ws, size_t ws_size,
                              hipStream_t stream) {
    const float* x     = (const float*)d_in[0];
    const float* pos   = (const float*)d_in[1];
    const int*   edges = (const int*)d_in[2];
    const float* ip_w1 = (const float*)d_in[4];
    const float* ip_b1 = (const float*)d_in[5];
    const float* ip_w2 = (const float*)d_in[6];
    const float* ip_b2 = (const float*)d_in[7];
    const float* ip_w3 = (const float*)d_in[8];
    const float* ip_b3 = (const float*)d_in[9];
    const float* bfour = (const float*)d_in[10];
    const float* mw1   = (const float*)d_in[11];
    const float* mb1   = (const float*)d_in[12];
    const float* mw2   = (const float*)d_in[13];
    const float* mb2   = (const float*)d_in[14];
    const float* mw3   = (const float*)d_in[15];
    const float* mb3   = (const float*)d_in[16];

    char* ws = (char*)d_ws;
    __bf16* hA = (__bf16*)ws;                                // 64 MB: h1, later final h
    __bf16* hB = hA + (size_t)N_NODES * HID;                 // 64 MB: h2 temp
    size_t off = (size_t)N_NODES * HID * 2 * 2;
    __bf16* wb = (__bf16*)(ws + off);                        // 1.125 MB bf16 weights
    off += (size_t)589824 * 2;
    off = (off + 255) & ~(size_t)255;
    char* scratch = ws + off;
    size_t avail = ws_size > off ? ws_size - off : 0;

    // chunk edges so m1 (eC*512) + m2 (eC*256) bf16 fit in remaining workspace
    int C = 1;
    while (C < 16 && ((size_t)N_EDGES / C) * (512 + 256) * 2 > avail) C <<= 1;
    const int eC  = N_EDGES / C;   // edges per chunk
    const int mbC = eC / 128;      // 128-row M-blocks per chunk

    __bf16* w2b  = wb;
    __bf16* w3b  = wb + 65536;
    __bf16* mw1b = wb + 131072;
    __bf16* mw2b = wb + 393216;
    __bf16* mw3b = wb + 524288;
    __bf16* m1c  = (__bf16*)scratch;
    __bf16* m2c  = m1c + (size_t)eC * 512;

    prep_kernel<<<2304, 256, 0, stream>>>(wb, ip_w2, ip_w3, mw1, mw2, mw3);

    // encoder: h1 -> hA; h2 = gelu(h1 W2^T+b2) -> hB; h = h2 W3^T+b3+fourier -> hA
    enc1_kernel<<<2048, 256, 0, stream>>>(x, ip_w1, ip_b1, hA);
    rgemm<false, false, true ><<<512, 256, 0, stream>>>(
        hA, w2b, ip_b2, hB, nullptr, nullptr, nullptr, nullptr, 2048, 0);
    rgemm<false, true,  false><<<512, 256, 0, stream>>>(
        hB, w3b, ip_b3, hA, nullptr, pos, bfour, nullptr, 2048, 0);

    for (int c = 0; c < C; c++) {
        int e0 = c * eC;
        mgemm<512, true ><<<mbC * 4, 256, 0, stream>>>(
            nullptr, hA, edges, mw1b, mb1, m1c, 4, 512, e0);
        mgemm<512, false><<<mbC * 2, 256, 0, stream>>>(
            m1c, nullptr, edges, mw2b, mb2, m2c, 2, 256, e0);
        int g3tiles = eC / 64;
        rgemm<true, false, false><<<(g3tiles < 512 ? g3tiles : 512), 256, 0, stream>>>(
            m2c, mw3b, mb3, nullptr, (float*)d_out, nullptr, nullptr, edges, g3tiles, e0);
    }
}

// Round 6
// 695.416 us; speedup vs baseline: 1.1805x; 1.1805x over previous
//
#include <hip/hip_runtime.h>
#include <math.h>

#define N_NODES 131072
#define N_DST   16384
#define DEG     16
#define HID     256
#define N_EDGES 262144

typedef __bf16 bf16_8 __attribute__((ext_vector_type(8)));
typedef float  f32_4  __attribute__((ext_vector_type(4)));

// tanh-approx gelu via hardware v_exp_f32: |err| <~1e-3, threshold is 2.2e-2
__device__ __forceinline__ float gelu_f(float v) {
    float t = 1.5957691216f * fmaf(v * v, 0.044715f * v, v);
    return v / (1.0f + __expf(-t));
}
__device__ __forceinline__ f32_4 zero4() {
    f32_4 z; z[0] = 0.f; z[1] = 0.f; z[2] = 0.f; z[3] = 0.f; return z;
}

// async global->LDS, 16B per lane. LDS side must be wave-uniform base + lane*16.
__device__ __forceinline__ void load_lds16(const __bf16* g, __bf16* l) {
    __builtin_amdgcn_global_load_lds(
        (__attribute__((address_space(1))) void*)g,
        (__attribute__((address_space(3))) void*)l, 16, 0, 0);
}

// ---------------- prep: fp32 -> bf16 weights ----------------
__global__ void prep_kernel(__bf16* __restrict__ out,
                            const float* __restrict__ w2,
                            const float* __restrict__ w3,
                            const float* __restrict__ mw1,
                            const float* __restrict__ mw2,
                            const float* __restrict__ mw3) {
    int stride = gridDim.x * blockDim.x;
    for (int i = blockIdx.x * blockDim.x + threadIdx.x; i < 589824; i += stride) {
        float v;
        if      (i <  65536) v = w2[i];
        else if (i < 131072) v = w3[i - 65536];
        else if (i < 393216) v = mw1[i - 131072];
        else if (i < 524288) v = mw2[i - 393216];
        else                 v = mw3[i - 524288];
        out[i] = (__bf16)v;
    }
}

// ---------------- encoder layer 1 (K=3): weights in registers, grid-stride ----
__global__ __launch_bounds__(256) void enc1_kernel(
    const float* __restrict__ x, const float* __restrict__ w1,
    const float* __restrict__ b1, __bf16* __restrict__ h1) {
    const int c8   = threadIdx.x & 31;
    const int nloc = threadIdx.x >> 5;
    float w[24], bb[8];
    #pragma unroll
    for (int i = 0; i < 6; i++) *(float4*)&w[i * 4] = ((const float4*)w1)[c8 * 6 + i];
    *(float4*)&bb[0] = ((const float4*)b1)[c8 * 2 + 0];
    *(float4*)&bb[4] = ((const float4*)b1)[c8 * 2 + 1];
    for (int n = blockIdx.x * 8 + nloc; n < N_NODES; n += gridDim.x * 8) {
        float x0 = x[n * 3 + 0], x1 = x[n * 3 + 1], x2 = x[n * 3 + 2];
        bf16_8 o;
        #pragma unroll
        for (int j = 0; j < 8; j++) {
            float v = fmaf(x2, w[j * 3 + 2],
                      fmaf(x1, w[j * 3 + 1],
                      fmaf(x0, w[j * 3 + 0], bb[j])));
            o[j] = (__bf16)gelu_f(v);
        }
        *(bf16_8*)&h1[(size_t)n * 256 + c8 * 8] = o;
    }
}

// ---------------- mgemm: C = epi(A @ W^T + b), all K-loop addresses hoisted ----
// 256 threads = 4 waves (2x2), block tile 128x128, wave tile 64x64, BK=64.
// Staging slot (i,tid): idx=i*256+tid, row=idx>>3, holds chunk kg=(idx&7)^(row&7).
template<int K, bool GATHER, bool GELU, bool POOL, bool FOURIER>
__global__ __launch_bounds__(256, 3) void mgemm(
    const __bf16* __restrict__ Ag, const __bf16* __restrict__ h,
    const int* __restrict__ edges, const __bf16* __restrict__ W,
    const float* __restrict__ bias, __bf16* __restrict__ Cb,
    float* __restrict__ Cf, const float* __restrict__ pos,
    const float* __restrict__ bfour, int NB, int Nfull, int e0)
{
    __shared__ __align__(16) __bf16 sA[128 * 64];
    __shared__ __align__(16) __bf16 sB[128 * 64];
    __shared__ int s_src[128];
    __shared__ int s_dst[128];

    const int tid  = threadIdx.x;
    const int mblk = blockIdx.x / NB;
    const int nblk = blockIdx.x % NB;
    const int m0 = mblk * 128, n0 = nblk * 128;
    const int wave = tid >> 6, lane = tid & 63, ln = lane & 15, quad = lane >> 4;
    const int wm = wave >> 1, wn = wave & 1;

    if (GATHER) {
        if (tid < 128) {
            int e = e0 + m0 + tid;
            s_src[tid] = edges[2 * e + 1];
            s_dst[tid] = edges[2 * e + 0];
        }
        __syncthreads();
    }

    // hoisted per-slot global base pointers (K-loop adds compile-time offsets only)
    const __bf16* pA[4];
    const __bf16* pAd[4];
    const __bf16* pB[4];
    #pragma unroll
    for (int i = 0; i < 4; i++) {
        int idx = i * 256 + tid;
        int row = idx >> 3, kg = (idx & 7) ^ (row & 7);
        if (GATHER) {
            pA[i]  = h + (size_t)s_src[row] * HID + kg * 8;
            pAd[i] = h + (size_t)s_dst[row] * HID + kg * 8;
        } else {
            pA[i]  = Ag + (size_t)(m0 + row) * K + kg * 8;
        }
        pB[i] = W + (size_t)(n0 + row) * K + kg * 8;
    }
    // hoisted LDS fragment bases (element idx); ks toggles chunk bit2, mt adds 1024
    const int ach = quad ^ (ln & 7);
    const int aof[2] = { (wm * 64 + ln) * 64 + ach * 8, (wm * 64 + ln) * 64 + (ach ^ 4) * 8 };
    const int bch = quad ^ (ln & 7);
    const int bof[2] = { (wn * 64 + ln) * 64 + bch * 8, (wn * 64 + ln) * 64 + (bch ^ 4) * 8 };

    f32_4 acc[4][4];
    #pragma unroll
    for (int i = 0; i < 4; i++)
        #pragma unroll
        for (int j = 0; j < 4; j++) acc[i][j] = zero4();

    #pragma unroll
    for (int kb = 0; kb < K / 64; kb++) {
        if (kb > 0) __syncthreads();   // previous tile consumed
        #pragma unroll
        for (int i = 0; i < 4; i++) {
            int idx = i * 256 + tid;
            const __bf16* g;
            if (GATHER) g = (kb < 4 ? pA[i] : pAd[i]) + (kb & 3) * 64;
            else        g = pA[i] + kb * 64;
            load_lds16(g, &sA[idx * 8]);
            load_lds16(pB[i] + kb * 64, &sB[idx * 8]);
        }
        __syncthreads();               // drains DMA (vmcnt) per barrier semantics
        #pragma unroll
        for (int ks = 0; ks < 2; ks++) {
            bf16_8 af[4], bfr[4];
            #pragma unroll
            for (int mt = 0; mt < 4; mt++) af[mt]  = *(const bf16_8*)&sA[aof[ks] + mt * 1024];
            #pragma unroll
            for (int nt = 0; nt < 4; nt++) bfr[nt] = *(const bf16_8*)&sB[bof[ks] + nt * 1024];
            #pragma unroll
            for (int mt = 0; mt < 4; mt++)
                #pragma unroll
                for (int nt = 0; nt < 4; nt++)
                    acc[mt][nt] = __builtin_amdgcn_mfma_f32_16x16x32_bf16(af[mt], bfr[nt], acc[mt][nt], 0, 0, 0);
        }
    }

    if (POOL) {
        // each 16-row m-tile is one dst group (DEG=16): in-register mean + bias
        #pragma unroll
        for (int nt = 0; nt < 4; nt++) {
            int col = n0 + wn * 64 + nt * 16 + ln;
            float bb = bias[col];
            #pragma unroll
            for (int mt = 0; mt < 4; mt++) {
                float s = acc[mt][nt][0] + acc[mt][nt][1] + acc[mt][nt][2] + acc[mt][nt][3];
                s += __shfl_xor(s, 16);
                s += __shfl_xor(s, 32);
                if (quad == 0) {
                    int dst = edges[2 * (e0 + m0 + wm * 64 + mt * 16)];
                    Cf[(size_t)dst * HID + col] = s * 0.0625f + bb;
                }
            }
        }
    } else {
        // epilogue: bias [+gelu] [+fourier]; LDS-transpose for coalesced 16B stores
        __syncthreads();
        __bf16* sw = ((wave & 2) ? sB : sA) + (wave & 1) * 4096;
        const bool iscos = FOURIER && ((n0 + wn * 64) < 128);
        #pragma unroll
        for (int nt = 0; nt < 4; nt++) {
            int col = n0 + wn * 64 + nt * 16 + ln;
            float bb = bias[col];
            float Bc0 = 0.f, Bc1 = 0.f;
            if (FOURIER) {
                int jm = col & 127;
                Bc0 = bfour[jm * 2 + 0];
                Bc1 = bfour[jm * 2 + 1];
            }
            #pragma unroll
            for (int mt = 0; mt < 4; mt++) {
                #pragma unroll
                for (int r = 0; r < 4; r++) {
                    int rowL = mt * 16 + quad * 4 + r;
                    float v = acc[mt][nt][r] + bb;
                    if (GELU) v = gelu_f(v);
                    if (FOURIER) {
                        int rowE = m0 + wm * 64 + rowL;
                        float f = 6.2831853071795864f *
                                  fmaf(pos[rowE * 2 + 1], Bc1, pos[rowE * 2 + 0] * Bc0);
                        v += iscos ? __cosf(f) : __sinf(f);
                    }
                    int colL = nt * 16 + ln;
                    sw[rowL * 64 + ((colL + rowL * 8) & 63)] = (__bf16)v;
                }
            }
        }
        __syncthreads();
        #pragma unroll
        for (int p = 0; p < 8; p++) {
            int rowL = p * 8 + (lane >> 3);
            int c8 = lane & 7;
            bf16_8 vv = *(const bf16_8*)&sw[rowL * 64 + ((c8 * 8 + rowL * 8) & 63)];
            int rowE = m0 + wm * 64 + rowL;
            *(bf16_8*)&Cb[(size_t)rowE * Nfull + n0 + wn * 64 + c8 * 8] = vv;
        }
    }
}

extern "C" void kernel_launch(void* const* d_in, const int* in_sizes, int n_in,
                              void* d_out, int out_size, void* d_ws, size_t ws_size,
                              hipStream_t stream) {
    const float* x     = (const float*)d_in[0];
    const float* pos   = (const float*)d_in[1];
    const int*   edges = (const int*)d_in[2];
    const float* ip_w1 = (const float*)d_in[4];
    const float* ip_b1 = (const float*)d_in[5];
    const float* ip_w2 = (const float*)d_in[6];
    const float* ip_b2 = (const float*)d_in[7];
    const float* ip_w3 = (const float*)d_in[8];
    const float* ip_b3 = (const float*)d_in[9];
    const float* bfour = (const float*)d_in[10];
    const float* mw1   = (const float*)d_in[11];
    const float* mb1   = (const float*)d_in[12];
    const float* mw2   = (const float*)d_in[13];
    const float* mb2   = (const float*)d_in[14];
    const float* mw3   = (const float*)d_in[15];
    const float* mb3   = (const float*)d_in[16];

    char* ws = (char*)d_ws;
    __bf16* hA = (__bf16*)ws;                                // 64 MB: h1, later final h
    __bf16* hB = hA + (size_t)N_NODES * HID;                 // 64 MB: h2 temp
    size_t off = (size_t)N_NODES * HID * 2 * 2;
    __bf16* wb = (__bf16*)(ws + off);                        // 1.125 MB bf16 weights
    off += (size_t)589824 * 2;
    off = (off + 255) & ~(size_t)255;
    char* scratch = ws + off;
    size_t avail = ws_size > off ? ws_size - off : 0;

    // chunk edges so m1 (eC*512) + m2 (eC*256) bf16 fit in remaining workspace
    int C = 1;
    while (C < 16 && ((size_t)N_EDGES / C) * (512 + 256) * 2 > avail) C <<= 1;
    const int eC  = N_EDGES / C;   // edges per chunk
    const int mbC = eC / 128;      // 128-row M-blocks per chunk

    __bf16* w2b  = wb;
    __bf16* w3b  = wb + 65536;
    __bf16* mw1b = wb + 131072;
    __bf16* mw2b = wb + 393216;
    __bf16* mw3b = wb + 524288;
    __bf16* m1c  = (__bf16*)scratch;
    __bf16* m2c  = m1c + (size_t)eC * 512;

    prep_kernel<<<2304, 256, 0, stream>>>(wb, ip_w2, ip_w3, mw1, mw2, mw3);

    // encoder: h1 -> hA; h2 = gelu(h1 W2^T+b2) -> hB; h = h2 W3^T+b3+fourier -> hA
    enc1_kernel<<<2048, 256, 0, stream>>>(x, ip_w1, ip_b1, hA);
    mgemm<256, false, true,  false, false><<<2048, 256, 0, stream>>>(
        hA, nullptr, nullptr, w2b, ip_b2, hB, nullptr, nullptr, nullptr, 2, 256, 0);
    mgemm<256, false, false, false, true ><<<2048, 256, 0, stream>>>(
        hB, nullptr, nullptr, w3b, ip_b3, hA, nullptr, pos, bfour, 2, 256, 0);

    for (int c = 0; c < C; c++) {
        int e0 = c * eC;
        mgemm<512, true,  true,  false, false><<<mbC * 4, 256, 0, stream>>>(
            nullptr, hA, edges, mw1b, mb1, m1c, nullptr, nullptr, nullptr, 4, 512, e0);
        mgemm<512, false, true,  false, false><<<mbC * 2, 256, 0, stream>>>(
            m1c, nullptr, edges, mw2b, mb2, m2c, nullptr, nullptr, nullptr, 2, 256, e0);
        mgemm<256, false, false, true,  false><<<mbC * 2, 256, 0, stream>>>(
            m2c, nullptr, edges, mw3b, mb3, nullptr, (float*)d_out, nullptr, nullptr, 2, 256, e0);
    }
}

// Round 7
// 585.555 us; speedup vs baseline: 1.4019x; 1.1876x over previous
//
#include <hip/hip_runtime.h>
#include <math.h>

#define N_NODES 131072
#define N_DST   16384
#define DEG     16
#define HID     256
#define N_EDGES 262144

typedef __bf16 bf16_8 __attribute__((ext_vector_type(8)));
typedef float  f32_4  __attribute__((ext_vector_type(4)));

// tanh-approx gelu via hardware v_exp_f32: |err| <~1e-3, threshold is 2.2e-2
__device__ __forceinline__ float gelu_f(float v) {
    float t = 1.5957691216f * fmaf(v * v, 0.044715f * v, v);
    return v / (1.0f + __expf(-t));
}
__device__ __forceinline__ f32_4 zero4() {
    f32_4 z; z[0] = 0.f; z[1] = 0.f; z[2] = 0.f; z[3] = 0.f; return z;
}

// async global->LDS, 16B per lane. LDS side must be wave-uniform base + lane*16.
__device__ __forceinline__ void load_lds16(const __bf16* g, __bf16* l) {
    __builtin_amdgcn_global_load_lds(
        (__attribute__((address_space(1))) void*)g,
        (__attribute__((address_space(3))) void*)l, 16, 0, 0);
}

// ---------------- prep: fp32 -> bf16 weights ----------------
__global__ void prep_kernel(__bf16* __restrict__ out,
                            const float* __restrict__ w2,
                            const float* __restrict__ w3,
                            const float* __restrict__ mw1,
                            const float* __restrict__ mw2,
                            const float* __restrict__ mw3) {
    int stride = gridDim.x * blockDim.x;
    for (int i = blockIdx.x * blockDim.x + threadIdx.x; i < 589824; i += stride) {
        float v;
        if      (i <  65536) v = w2[i];
        else if (i < 131072) v = w3[i - 65536];
        else if (i < 393216) v = mw1[i - 131072];
        else if (i < 524288) v = mw2[i - 393216];
        else                 v = mw3[i - 524288];
        out[i] = (__bf16)v;
    }
}

// ---------------- encoder layer 1 (K=3): weights in registers, grid-stride ----
__global__ __launch_bounds__(256) void enc1_kernel(
    const float* __restrict__ x, const float* __restrict__ w1,
    const float* __restrict__ b1, __bf16* __restrict__ h1) {
    const int c8   = threadIdx.x & 31;
    const int nloc = threadIdx.x >> 5;
    float w[24], bb[8];
    #pragma unroll
    for (int i = 0; i < 6; i++) *(float4*)&w[i * 4] = ((const float4*)w1)[c8 * 6 + i];
    *(float4*)&bb[0] = ((const float4*)b1)[c8 * 2 + 0];
    *(float4*)&bb[4] = ((const float4*)b1)[c8 * 2 + 1];
    for (int n = blockIdx.x * 8 + nloc; n < N_NODES; n += gridDim.x * 8) {
        float x0 = x[n * 3 + 0], x1 = x[n * 3 + 1], x2 = x[n * 3 + 2];
        bf16_8 o;
        #pragma unroll
        for (int j = 0; j < 8; j++) {
            float v = fmaf(x2, w[j * 3 + 2],
                      fmaf(x1, w[j * 3 + 1],
                      fmaf(x0, w[j * 3 + 0], bb[j])));
            o[j] = (__bf16)gelu_f(v);
        }
        *(bf16_8*)&h1[(size_t)n * 256 + c8 * 8] = o;
    }
}

// ---------------- mgemm: C-tile 128x128, 4 waves 2x2, BK=64, hoisted addresses ----
// GMODE: 0 = dense A (stride K), 1 = src-gather rows (h[edges[2e+1]], K=256),
//        2 = group-dst gather (h[edges[2*16*row]], K=256; row = dst-group).
// Epilogues: POOL_ (mean of gelu(acc+b) over 16-row groups -> bf16), F32OUT
// (bias, fp32 direct store), else transpose-store bf16 with optional GELU_/
// FOURIER_/DADD_ (v = gelu(s + b + d[group])).
template<int K, int GMODE, int WLD, int WOFF, bool BIAS, bool GELU_, bool FOURIER_,
         bool DADD_, bool POOL_, bool F32OUT>
__global__ __launch_bounds__(256, 3) void mgemm(
    const __bf16* __restrict__ Ag, const __bf16* __restrict__ h,
    const int* __restrict__ edges, const __bf16* __restrict__ W,
    const float* __restrict__ bias, __bf16* __restrict__ Cb,
    float* __restrict__ Cf, const __bf16* __restrict__ dmat,
    const float* __restrict__ pos, const float* __restrict__ bfour,
    int NB, int Nfull, int e0)
{
    __shared__ __align__(16) __bf16 sA[128 * 64];
    __shared__ __align__(16) __bf16 sB[128 * 64];
    __shared__ int s_idx[128];

    const int tid  = threadIdx.x;
    const int mblk = blockIdx.x / NB;
    const int nblk = blockIdx.x % NB;
    const int m0 = mblk * 128, n0 = nblk * 128;
    const int wave = tid >> 6, lane = tid & 63, ln = lane & 15, quad = lane >> 4;
    const int wm = wave >> 1, wn = wave & 1;

    if (GMODE) {
        if (tid < 128) {
            int r = m0 + tid;
            s_idx[tid] = (GMODE == 1) ? edges[2 * (e0 + r) + 1]
                                      : edges[2 * (DEG * r)];
        }
        __syncthreads();
    }

    // hoisted per-slot global base pointers (K-loop adds compile-time offsets)
    const __bf16* pA[4];
    const __bf16* pB[4];
    #pragma unroll
    for (int i = 0; i < 4; i++) {
        int idx = i * 256 + tid;
        int row = idx >> 3, kg = (idx & 7) ^ (row & 7);
        pA[i] = GMODE ? h + (size_t)s_idx[row] * HID + kg * 8
                      : Ag + (size_t)(m0 + row) * K + kg * 8;
        pB[i] = W + (size_t)(n0 + row) * WLD + WOFF + kg * 8;
    }
    // hoisted LDS fragment bases; ks toggles chunk bit2 (xor 4), mt/nt add 1024
    const int ach = quad ^ (ln & 7);
    const int aof[2] = { (wm * 64 + ln) * 64 + ach * 8, (wm * 64 + ln) * 64 + (ach ^ 4) * 8 };
    const int bof[2] = { (wn * 64 + ln) * 64 + ach * 8, (wn * 64 + ln) * 64 + (ach ^ 4) * 8 };

    f32_4 acc[4][4];
    #pragma unroll
    for (int i = 0; i < 4; i++)
        #pragma unroll
        for (int j = 0; j < 4; j++) acc[i][j] = zero4();

    #pragma unroll
    for (int kb = 0; kb < K / 64; kb++) {
        if (kb > 0) __syncthreads();
        #pragma unroll
        for (int i = 0; i < 4; i++) {
            int idx = i * 256 + tid;
            load_lds16(pA[i] + kb * 64, &sA[idx * 8]);
            load_lds16(pB[i] + kb * 64, &sB[idx * 8]);
        }
        __syncthreads();               // drains DMA (vmcnt) per barrier semantics
        #pragma unroll
        for (int ks = 0; ks < 2; ks++) {
            bf16_8 af[4], bfr[4];
            #pragma unroll
            for (int mt = 0; mt < 4; mt++) af[mt]  = *(const bf16_8*)&sA[aof[ks] + mt * 1024];
            #pragma unroll
            for (int nt = 0; nt < 4; nt++) bfr[nt] = *(const bf16_8*)&sB[bof[ks] + nt * 1024];
            #pragma unroll
            for (int mt = 0; mt < 4; mt++)
                #pragma unroll
                for (int nt = 0; nt < 4; nt++)
                    acc[mt][nt] = __builtin_amdgcn_mfma_f32_16x16x32_bf16(af[mt], bfr[nt], acc[mt][nt], 0, 0, 0);
        }
    }

    if (POOL_) {
        // pooled mean of gelu(acc+bias) over each 16-row (dst-group) m-tile
        #pragma unroll
        for (int nt = 0; nt < 4; nt++) {
            int col = n0 + wn * 64 + nt * 16 + ln;
            float bb = BIAS ? bias[col] : 0.f;
            #pragma unroll
            for (int mt = 0; mt < 4; mt++) {
                float s = gelu_f(acc[mt][nt][0] + bb) + gelu_f(acc[mt][nt][1] + bb)
                        + gelu_f(acc[mt][nt][2] + bb) + gelu_f(acc[mt][nt][3] + bb);
                s += __shfl_xor(s, 16);
                s += __shfl_xor(s, 32);
                if (quad == 0) {
                    int eg  = e0 + m0 + wm * 64 + mt * 16;
                    int dstn = edges[2 * eg];
                    Cb[(size_t)dstn * HID + col] = (__bf16)(s * 0.0625f);
                }
            }
        }
    } else if (F32OUT) {
        #pragma unroll
        for (int nt = 0; nt < 4; nt++) {
            int col = n0 + wn * 64 + nt * 16 + ln;
            float bb = BIAS ? bias[col] : 0.f;
            #pragma unroll
            for (int mt = 0; mt < 4; mt++) {
                #pragma unroll
                for (int r = 0; r < 4; r++) {
                    int rowE = m0 + wm * 64 + mt * 16 + quad * 4 + r;
                    Cf[(size_t)rowE * Nfull + col] = acc[mt][nt][r] + bb;
                }
            }
        }
    } else {
        // bias [+gelu] [+fourier] -> LDS transpose -> [+d, gelu] -> 16B stores
        __syncthreads();
        __bf16* sw = ((wave & 2) ? sB : sA) + (wave & 1) * 4096;
        const bool iscos = FOURIER_ && ((n0 + wn * 64) < 128);
        #pragma unroll
        for (int nt = 0; nt < 4; nt++) {
            int col = n0 + wn * 64 + nt * 16 + ln;
            float bb = BIAS ? bias[col] : 0.f;
            float Bc0 = 0.f, Bc1 = 0.f;
            if (FOURIER_) {
                int jm = col & 127;
                Bc0 = bfour[jm * 2 + 0];
                Bc1 = bfour[jm * 2 + 1];
            }
            #pragma unroll
            for (int mt = 0; mt < 4; mt++) {
                #pragma unroll
                for (int r = 0; r < 4; r++) {
                    int rowL = mt * 16 + quad * 4 + r;
                    float v = acc[mt][nt][r] + bb;
                    if (GELU_) v = gelu_f(v);
                    if (FOURIER_) {
                        int rowE = m0 + wm * 64 + rowL;
                        float f = 6.2831853071795864f *
                                  fmaf(pos[rowE * 2 + 1], Bc1, pos[rowE * 2 + 0] * Bc0);
                        v += iscos ? __cosf(f) : __sinf(f);
                    }
                    int colL = nt * 16 + ln;
                    sw[rowL * 64 + ((colL + rowL * 8) & 63)] = (__bf16)v;
                }
            }
        }
        __syncthreads();
        #pragma unroll
        for (int p = 0; p < 8; p++) {
            int rowL = p * 8 + (lane >> 3);
            int c8 = lane & 7;
            bf16_8 vv = *(const bf16_8*)&sw[rowL * 64 + ((c8 * 8 + rowL * 8) & 63)];
            int rowE = m0 + wm * 64 + rowL;
            if (DADD_) {
                int g = (e0 + rowE) >> 4;  // dst = e>>4 by construction (repeat/arange)
                bf16_8 dd = *(const bf16_8*)&dmat[(size_t)g * 512 + n0 + wn * 64 + c8 * 8];
                #pragma unroll
                for (int j = 0; j < 8; j++)
                    vv[j] = (__bf16)gelu_f((float)vv[j] + (float)dd[j]);
            }
            *(bf16_8*)&Cb[(size_t)rowE * Nfull + n0 + wn * 64 + c8 * 8] = vv;
        }
    }
}

extern "C" void kernel_launch(void* const* d_in, const int* in_sizes, int n_in,
                              void* d_out, int out_size, void* d_ws, size_t ws_size,
                              hipStream_t stream) {
    const float* x     = (const float*)d_in[0];
    const float* pos   = (const float*)d_in[1];
    const int*   edges = (const int*)d_in[2];
    const float* ip_w1 = (const float*)d_in[4];
    const float* ip_b1 = (const float*)d_in[5];
    const float* ip_w2 = (const float*)d_in[6];
    const float* ip_b2 = (const float*)d_in[7];
    const float* ip_w3 = (const float*)d_in[8];
    const float* ip_b3 = (const float*)d_in[9];
    const float* bfour = (const float*)d_in[10];
    const float* mw1   = (const float*)d_in[11];
    const float* mb1   = (const float*)d_in[12];
    const float* mw2   = (const float*)d_in[13];
    const float* mb2   = (const float*)d_in[14];
    const float* mw3   = (const float*)d_in[15];
    const float* mb3   = (const float*)d_in[16];

    char* ws = (char*)d_ws;
    __bf16* hA = (__bf16*)ws;                                // 64 MB: h1 / final h
    __bf16* hB = hA + (size_t)N_NODES * HID;                 // 64 MB: h2 temp
    size_t off = (size_t)N_NODES * HID * 2 * 2;
    __bf16* wb = (__bf16*)(ws + off);                        // 1.125 MB bf16 weights
    off += (size_t)589824 * 2;
    off = (off + 255) & ~(size_t)255;
    __bf16* dbuf = (__bf16*)(ws + off);                      // 16 MB: d = h_dst @ W1b^T
    off += (size_t)N_DST * 512 * 2;
    __bf16* p2 = (__bf16*)(ws + off);                        // 8 MB: pooled m2
    off += (size_t)N_DST * HID * 2;
    off = (off + 255) & ~(size_t)255;
    char* scratch = ws + off;
    size_t avail = ws_size > off ? ws_size - off : 0;

    // chunk edges so m1 (eC*512 bf16) fits in remaining workspace
    int C = 1;
    while (C < 16 && ((size_t)N_EDGES / C) * 512 * 2 > avail) C <<= 1;
    const int eC  = N_EDGES / C;
    const int mbC = eC / 128;

    __bf16* w2b  = wb;
    __bf16* w3b  = wb + 65536;
    __bf16* mw1b = wb + 131072;
    __bf16* mw2b = wb + 393216;
    __bf16* mw3b = wb + 524288;
    __bf16* m1c  = (__bf16*)scratch;

    prep_kernel<<<2304, 256, 0, stream>>>(wb, ip_w2, ip_w3, mw1, mw2, mw3);

    // encoder: h1 -> hA; h2 -> hB; h (fourier) -> hA
    enc1_kernel<<<2048, 256, 0, stream>>>(x, ip_w1, ip_b1, hA);
    mgemm<256, 0, 256, 0, true, true,  false, false, false, false><<<2048, 256, 0, stream>>>(
        hA, nullptr, nullptr, w2b, ip_b2, hB, nullptr, nullptr, nullptr, nullptr, 2, 256, 0);
    mgemm<256, 0, 256, 0, true, false, true,  false, false, false><<<2048, 256, 0, stream>>>(
        hB, nullptr, nullptr, w3b, ip_b3, hA, nullptr, nullptr, pos, bfour, 2, 256, 0);

    // d[g] = h[dst(g)] @ W1b^T  (16384 x 512, K=256) -- no bias, raw store
    mgemm<256, 2, 512, 256, false, false, false, false, false, false><<<512, 256, 0, stream>>>(
        nullptr, hA, edges, mw1b, nullptr, dbuf, nullptr, nullptr, nullptr, nullptr, 4, 512, 0);

    for (int c = 0; c < C; c++) {
        int e0 = c * eC;
        // m1 = gelu(h[src] @ W1a^T + b1 + d[e>>4])  (eC x 512, K=256)
        mgemm<256, 1, 512, 0, true, false, false, true, false, false><<<mbC * 4, 256, 0, stream>>>(
            nullptr, hA, edges, mw1b, mb1, m1c, nullptr, dbuf, nullptr, nullptr, 4, 512, e0);
        // p2[dst] = mean_group(gelu(m1 @ W2^T + b2))  (pool fused; K=512)
        mgemm<512, 0, 512, 0, true, false, false, false, true, false><<<mbC * 2, 256, 0, stream>>>(
            m1c, nullptr, edges, mw2b, mb2, p2, nullptr, nullptr, nullptr, nullptr, 2, 256, e0);
    }
    // out = p2 @ W3^T + b3  (16384 x 256, K=256), fp32
    mgemm<256, 0, 256, 0, true, false, false, false, false, true><<<256, 256, 0, stream>>>(
        p2, nullptr, nullptr, mw3b, mb3, nullptr, (float*)d_out, nullptr, nullptr, nullptr, 2, 256, 0);
}

// Round 8
// 573.808 us; speedup vs baseline: 1.4306x; 1.0205x over previous
//
#include <hip/hip_runtime.h>
#include <math.h>

#define N_NODES 131072
#define N_DST   16384
#define DEG     16
#define HID     256
#define N_EDGES 262144

typedef __bf16 bf16_8 __attribute__((ext_vector_type(8)));
typedef float  f32_4  __attribute__((ext_vector_type(4)));

// tanh-approx gelu via hardware v_exp_f32: |err| <~1e-3, threshold is 2.2e-2
__device__ __forceinline__ float gelu_f(float v) {
    float t = 1.5957691216f * fmaf(v * v, 0.044715f * v, v);
    return v / (1.0f + __expf(-t));
}
__device__ __forceinline__ f32_4 zero4() {
    f32_4 z; z[0] = 0.f; z[1] = 0.f; z[2] = 0.f; z[3] = 0.f; return z;
}

// ---------------- prep: fp32 -> bf16 weights ----------------
__global__ void prep_kernel(__bf16* __restrict__ out,
                            const float* __restrict__ w2,
                            const float* __restrict__ w3,
                            const float* __restrict__ mw1,
                            const float* __restrict__ mw2,
                            const float* __restrict__ mw3) {
    int stride = gridDim.x * blockDim.x;
    for (int i = blockIdx.x * blockDim.x + threadIdx.x; i < 589824; i += stride) {
        float v;
        if      (i <  65536) v = w2[i];
        else if (i < 131072) v = w3[i - 65536];
        else if (i < 393216) v = mw1[i - 131072];
        else if (i < 524288) v = mw2[i - 393216];
        else                 v = mw3[i - 524288];
        out[i] = (__bf16)v;
    }
}

// ---------------- encoder layer 1 (K=3): weights in registers, grid-stride ----
__global__ __launch_bounds__(256) void enc1_kernel(
    const float* __restrict__ x, const float* __restrict__ w1,
    const float* __restrict__ b1, __bf16* __restrict__ h1) {
    const int c8   = threadIdx.x & 31;
    const int nloc = threadIdx.x >> 5;
    float w[24], bb[8];
    #pragma unroll
    for (int i = 0; i < 6; i++) *(float4*)&w[i * 4] = ((const float4*)w1)[c8 * 6 + i];
    *(float4*)&bb[0] = ((const float4*)b1)[c8 * 2 + 0];
    *(float4*)&bb[4] = ((const float4*)b1)[c8 * 2 + 1];
    for (int n = blockIdx.x * 8 + nloc; n < N_NODES; n += gridDim.x * 8) {
        float x0 = x[n * 3 + 0], x1 = x[n * 3 + 1], x2 = x[n * 3 + 2];
        bf16_8 o;
        #pragma unroll
        for (int j = 0; j < 8; j++) {
            float v = fmaf(x2, w[j * 3 + 2],
                      fmaf(x1, w[j * 3 + 1],
                      fmaf(x0, w[j * 3 + 0], bb[j])));
            o[j] = (__bf16)gelu_f(v);
        }
        *(bf16_8*)&h1[(size_t)n * 256 + c8 * 8] = o;
    }
}

// ---------------- mgemm: C-tile 128x128, 4 waves 2x2, BK=64 ----------------
// Staging: register-prefetch double-buffer — slab kb+1 is loaded into VGPRs
// (plain global_load_dwordx4) while slab kb computes from LDS; the loads'
// vmcnt wait lands at the next iteration's ds_write, hiding load latency
// without the global_load_lds full-drain barrier.
// GMODE: 0 = dense A, 1 = src-gather rows, 2 = group-dst gather rows.
template<int K, int GMODE, int WLD, int WOFF, bool BIAS, bool GELU_, bool FOURIER_,
         bool DADD_, bool POOL_, bool F32OUT>
__global__ __launch_bounds__(256, 3) void mgemm(
    const __bf16* __restrict__ Ag, const __bf16* __restrict__ h,
    const int* __restrict__ edges, const __bf16* __restrict__ W,
    const float* __restrict__ bias, __bf16* __restrict__ Cb,
    float* __restrict__ Cf, const __bf16* __restrict__ dmat,
    const float* __restrict__ pos, const float* __restrict__ bfour,
    int NB, int Nfull, int e0)
{
    __shared__ __align__(16) __bf16 sA[128 * 64];
    __shared__ __align__(16) __bf16 sB[128 * 64];
    __shared__ int s_idx[128];

    const int tid  = threadIdx.x;
    const int mblk = blockIdx.x / NB;
    const int nblk = blockIdx.x % NB;
    const int m0 = mblk * 128, n0 = nblk * 128;
    const int wave = tid >> 6, lane = tid & 63, ln = lane & 15, quad = lane >> 4;
    const int wm = wave >> 1, wn = wave & 1;

    if (GMODE) {
        if (tid < 128) {
            int r = m0 + tid;
            s_idx[tid] = (GMODE == 1) ? edges[2 * (e0 + r) + 1]
                                      : edges[2 * (DEG * r)];
        }
        __syncthreads();
    }

    // hoisted per-slot global base pointers (K-loop adds compile-time offsets)
    const __bf16* pA[4];
    const __bf16* pB[4];
    #pragma unroll
    for (int i = 0; i < 4; i++) {
        int idx = i * 256 + tid;
        int row = idx >> 3, kg = (idx & 7) ^ (row & 7);
        pA[i] = GMODE ? h + (size_t)s_idx[row] * HID + kg * 8
                      : Ag + (size_t)(m0 + row) * K + kg * 8;
        pB[i] = W + (size_t)(n0 + row) * WLD + WOFF + kg * 8;
    }
    // hoisted LDS fragment bases; ks toggles chunk bit2 (xor 4), mt/nt add 1024
    const int ach = quad ^ (ln & 7);
    const int aof[2] = { (wm * 64 + ln) * 64 + ach * 8, (wm * 64 + ln) * 64 + (ach ^ 4) * 8 };
    const int bof[2] = { (wn * 64 + ln) * 64 + ach * 8, (wn * 64 + ln) * 64 + (ach ^ 4) * 8 };

    f32_4 acc[4][4];
    #pragma unroll
    for (int i = 0; i < 4; i++)
        #pragma unroll
        for (int j = 0; j < 4; j++) acc[i][j] = zero4();

    // prologue: slab 0 -> registers
    bf16_8 ar[4], br[4];
    #pragma unroll
    for (int i = 0; i < 4; i++) {
        ar[i] = *(const bf16_8*)pA[i];
        br[i] = *(const bf16_8*)pB[i];
    }

    #pragma unroll
    for (int kb = 0; kb < K / 64; kb++) {
        if (kb > 0) __syncthreads();   // previous slab's fragment reads complete
        #pragma unroll
        for (int i = 0; i < 4; i++) {  // vmcnt wait for ar/br lands here
            int idx = i * 256 + tid;
            *(bf16_8*)&sA[idx * 8] = ar[i];
            *(bf16_8*)&sB[idx * 8] = br[i];
        }
        __syncthreads();
        if (kb + 1 < K / 64) {         // prefetch next slab; overlaps MFMA below
            #pragma unroll
            for (int i = 0; i < 4; i++) {
                ar[i] = *(const bf16_8*)(pA[i] + (kb + 1) * 64);
                br[i] = *(const bf16_8*)(pB[i] + (kb + 1) * 64);
            }
        }
        #pragma unroll
        for (int ks = 0; ks < 2; ks++) {
            bf16_8 af[4], bfr[4];
            #pragma unroll
            for (int mt = 0; mt < 4; mt++) af[mt]  = *(const bf16_8*)&sA[aof[ks] + mt * 1024];
            #pragma unroll
            for (int nt = 0; nt < 4; nt++) bfr[nt] = *(const bf16_8*)&sB[bof[ks] + nt * 1024];
            #pragma unroll
            for (int mt = 0; mt < 4; mt++)
                #pragma unroll
                for (int nt = 0; nt < 4; nt++)
                    acc[mt][nt] = __builtin_amdgcn_mfma_f32_16x16x32_bf16(af[mt], bfr[nt], acc[mt][nt], 0, 0, 0);
        }
    }

    if (POOL_) {
        // pooled mean of gelu(acc+bias) over each 16-row (dst-group) m-tile
        #pragma unroll
        for (int nt = 0; nt < 4; nt++) {
            int col = n0 + wn * 64 + nt * 16 + ln;
            float bb = BIAS ? bias[col] : 0.f;
            #pragma unroll
            for (int mt = 0; mt < 4; mt++) {
                float s = gelu_f(acc[mt][nt][0] + bb) + gelu_f(acc[mt][nt][1] + bb)
                        + gelu_f(acc[mt][nt][2] + bb) + gelu_f(acc[mt][nt][3] + bb);
                s += __shfl_xor(s, 16);
                s += __shfl_xor(s, 32);
                if (quad == 0) {
                    int eg  = e0 + m0 + wm * 64 + mt * 16;
                    int dstn = edges[2 * eg];
                    Cb[(size_t)dstn * HID + col] = (__bf16)(s * 0.0625f);
                }
            }
        }
    } else if (F32OUT) {
        #pragma unroll
        for (int nt = 0; nt < 4; nt++) {
            int col = n0 + wn * 64 + nt * 16 + ln;
            float bb = BIAS ? bias[col] : 0.f;
            #pragma unroll
            for (int mt = 0; mt < 4; mt++) {
                #pragma unroll
                for (int r = 0; r < 4; r++) {
                    int rowE = m0 + wm * 64 + mt * 16 + quad * 4 + r;
                    Cf[(size_t)rowE * Nfull + col] = acc[mt][nt][r] + bb;
                }
            }
        }
    } else {
        // bias [+gelu] [+fourier] -> LDS transpose -> [+d, gelu] -> 16B stores
        __syncthreads();
        __bf16* sw = ((wave & 2) ? sB : sA) + (wave & 1) * 4096;
        const bool iscos = FOURIER_ && ((n0 + wn * 64) < 128);
        #pragma unroll
        for (int nt = 0; nt < 4; nt++) {
            int col = n0 + wn * 64 + nt * 16 + ln;
            float bb = BIAS ? bias[col] : 0.f;
            float Bc0 = 0.f, Bc1 = 0.f;
            if (FOURIER_) {
                int jm = col & 127;
                Bc0 = bfour[jm * 2 + 0];
                Bc1 = bfour[jm * 2 + 1];
            }
            #pragma unroll
            for (int mt = 0; mt < 4; mt++) {
                #pragma unroll
                for (int r = 0; r < 4; r++) {
                    int rowL = mt * 16 + quad * 4 + r;
                    float v = acc[mt][nt][r] + bb;
                    if (GELU_) v = gelu_f(v);
                    if (FOURIER_) {
                        int rowE = m0 + wm * 64 + rowL;
                        float f = 6.2831853071795864f *
                                  fmaf(pos[rowE * 2 + 1], Bc1, pos[rowE * 2 + 0] * Bc0);
                        v += iscos ? __cosf(f) : __sinf(f);
                    }
                    int colL = nt * 16 + ln;
                    sw[rowL * 64 + ((colL + rowL * 8) & 63)] = (__bf16)v;
                }
            }
        }
        __syncthreads();
        #pragma unroll
        for (int p = 0; p < 8; p++) {
            int rowL = p * 8 + (lane >> 3);
            int c8 = lane & 7;
            bf16_8 vv = *(const bf16_8*)&sw[rowL * 64 + ((c8 * 8 + rowL * 8) & 63)];
            int rowE = m0 + wm * 64 + rowL;
            if (DADD_) {
                int g = (e0 + rowE) >> 4;  // dst = e>>4 by construction (repeat/arange)
                bf16_8 dd = *(const bf16_8*)&dmat[(size_t)g * 512 + n0 + wn * 64 + c8 * 8];
                #pragma unroll
                for (int j = 0; j < 8; j++)
                    vv[j] = (__bf16)gelu_f((float)vv[j] + (float)dd[j]);
            }
            *(bf16_8*)&Cb[(size_t)rowE * Nfull + n0 + wn * 64 + c8 * 8] = vv;
        }
    }
}

extern "C" void kernel_launch(void* const* d_in, const int* in_sizes, int n_in,
                              void* d_out, int out_size, void* d_ws, size_t ws_size,
                              hipStream_t stream) {
    const float* x     = (const float*)d_in[0];
    const float* pos   = (const float*)d_in[1];
    const int*   edges = (const int*)d_in[2];
    const float* ip_w1 = (const float*)d_in[4];
    const float* ip_b1 = (const float*)d_in[5];
    const float* ip_w2 = (const float*)d_in[6];
    const float* ip_b2 = (const float*)d_in[7];
    const float* ip_w3 = (const float*)d_in[8];
    const float* ip_b3 = (const float*)d_in[9];
    const float* bfour = (const float*)d_in[10];
    const float* mw1   = (const float*)d_in[11];
    const float* mb1   = (const float*)d_in[12];
    const float* mw2   = (const float*)d_in[13];
    const float* mb2   = (const float*)d_in[14];
    const float* mw3   = (const float*)d_in[15];
    const float* mb3   = (const float*)d_in[16];

    char* ws = (char*)d_ws;
    __bf16* hA = (__bf16*)ws;                                // 64 MB: h1 / final h
    __bf16* hB = hA + (size_t)N_NODES * HID;                 // 64 MB: h2 temp
    size_t off = (size_t)N_NODES * HID * 2 * 2;
    __bf16* wb = (__bf16*)(ws + off);                        // 1.125 MB bf16 weights
    off += (size_t)589824 * 2;
    off = (off + 255) & ~(size_t)255;
    __bf16* dbuf = (__bf16*)(ws + off);                      // 16 MB: d = h_dst @ W1b^T
    off += (size_t)N_DST * 512 * 2;
    __bf16* p2 = (__bf16*)(ws + off);                        // 8 MB: pooled m2
    off += (size_t)N_DST * HID * 2;
    off = (off + 255) & ~(size_t)255;
    char* scratch = ws + off;
    size_t avail = ws_size > off ? ws_size - off : 0;

    // chunk edges so m1 (eC*512 bf16) fits in remaining workspace
    int C = 1;
    while (C < 16 && ((size_t)N_EDGES / C) * 512 * 2 > avail) C <<= 1;
    const int eC  = N_EDGES / C;
    const int mbC = eC / 128;

    __bf16* w2b  = wb;
    __bf16* w3b  = wb + 65536;
    __bf16* mw1b = wb + 131072;
    __bf16* mw2b = wb + 393216;
    __bf16* mw3b = wb + 524288;
    __bf16* m1c  = (__bf16*)scratch;

    prep_kernel<<<2304, 256, 0, stream>>>(wb, ip_w2, ip_w3, mw1, mw2, mw3);

    // encoder: h1 -> hA; h2 -> hB; h (fourier) -> hA
    enc1_kernel<<<2048, 256, 0, stream>>>(x, ip_w1, ip_b1, hA);
    mgemm<256, 0, 256, 0, true, true,  false, false, false, false><<<2048, 256, 0, stream>>>(
        hA, nullptr, nullptr, w2b, ip_b2, hB, nullptr, nullptr, nullptr, nullptr, 2, 256, 0);
    mgemm<256, 0, 256, 0, true, false, true,  false, false, false><<<2048, 256, 0, stream>>>(
        hB, nullptr, nullptr, w3b, ip_b3, hA, nullptr, nullptr, pos, bfour, 2, 256, 0);

    // d[g] = h[dst(g)] @ W1b^T  (16384 x 512, K=256) -- no bias, raw store
    mgemm<256, 2, 512, 256, false, false, false, false, false, false><<<512, 256, 0, stream>>>(
        nullptr, hA, edges, mw1b, nullptr, dbuf, nullptr, nullptr, nullptr, nullptr, 4, 512, 0);

    for (int c = 0; c < C; c++) {
        int e0 = c * eC;
        // m1 = gelu(h[src] @ W1a^T + b1 + d[e>>4])  (eC x 512, K=256)
        mgemm<256, 1, 512, 0, true, false, false, true, false, false><<<mbC * 4, 256, 0, stream>>>(
            nullptr, hA, edges, mw1b, mb1, m1c, nullptr, dbuf, nullptr, nullptr, 4, 512, e0);
        // p2[dst] = mean_group(gelu(m1 @ W2^T + b2))  (pool fused; K=512)
        mgemm<512, 0, 512, 0, true, false, false, false, true, false><<<mbC * 2, 256, 0, stream>>>(
            m1c, nullptr, edges, mw2b, mb2, p2, nullptr, nullptr, nullptr, nullptr, 2, 256, e0);
    }
    // out = p2 @ W3^T + b3  (16384 x 256, K=256), fp32
    mgemm<256, 0, 256, 0, true, false, false, false, false, true><<<256, 256, 0, stream>>>(
        p2, nullptr, nullptr, mw3b, mb3, nullptr, (float*)d_out, nullptr, nullptr, nullptr, 2, 256, 0);
}

// Round 9
// 572.674 us; speedup vs baseline: 1.4335x; 1.0020x over previous
//
#include <hip/hip_runtime.h>
#include <math.h>

#define N_NODES 131072
#define N_DST   16384
#define DEG     16
#define HID     256
#define N_EDGES 262144

typedef __bf16 bf16_8 __attribute__((ext_vector_type(8)));
typedef float  f32_4  __attribute__((ext_vector_type(4)));

// tanh-approx gelu via hardware v_exp_f32: |err| <~1e-3, threshold is 2.2e-2
__device__ __forceinline__ float gelu_f(float v) {
    float t = 1.5957691216f * fmaf(v * v, 0.044715f * v, v);
    return v / (1.0f + __expf(-t));
}
__device__ __forceinline__ f32_4 zero4() {
    f32_4 z; z[0] = 0.f; z[1] = 0.f; z[2] = 0.f; z[3] = 0.f; return z;
}

// async global->LDS, 16B per lane. LDS side must be wave-uniform base + lane*16.
__device__ __forceinline__ void load_lds16(const __bf16* g, __bf16* l) {
    __builtin_amdgcn_global_load_lds(
        (__attribute__((address_space(1))) void*)g,
        (__attribute__((address_space(3))) void*)l, 16, 0, 0);
}

// ---------------- prep: fp32 -> bf16 weights ----------------
__global__ void prep_kernel(__bf16* __restrict__ out,
                            const float* __restrict__ w2,
                            const float* __restrict__ w3,
                            const float* __restrict__ mw1,
                            const float* __restrict__ mw2,
                            const float* __restrict__ mw3) {
    int stride = gridDim.x * blockDim.x;
    for (int i = blockIdx.x * blockDim.x + threadIdx.x; i < 589824; i += stride) {
        float v;
        if      (i <  65536) v = w2[i];
        else if (i < 131072) v = w3[i - 65536];
        else if (i < 393216) v = mw1[i - 131072];
        else if (i < 524288) v = mw2[i - 393216];
        else                 v = mw3[i - 524288];
        out[i] = (__bf16)v;
    }
}

// ---------------- encoder layer 1 (K=3): weights in registers, grid-stride ----
__global__ __launch_bounds__(256) void enc1_kernel(
    const float* __restrict__ x, const float* __restrict__ w1,
    const float* __restrict__ b1, __bf16* __restrict__ h1) {
    const int c8   = threadIdx.x & 31;
    const int nloc = threadIdx.x >> 5;
    float w[24], bb[8];
    #pragma unroll
    for (int i = 0; i < 6; i++) *(float4*)&w[i * 4] = ((const float4*)w1)[c8 * 6 + i];
    *(float4*)&bb[0] = ((const float4*)b1)[c8 * 2 + 0];
    *(float4*)&bb[4] = ((const float4*)b1)[c8 * 2 + 1];
    for (int n = blockIdx.x * 8 + nloc; n < N_NODES; n += gridDim.x * 8) {
        float x0 = x[n * 3 + 0], x1 = x[n * 3 + 1], x2 = x[n * 3 + 2];
        bf16_8 o;
        #pragma unroll
        for (int j = 0; j < 8; j++) {
            float v = fmaf(x2, w[j * 3 + 2],
                      fmaf(x1, w[j * 3 + 1],
                      fmaf(x0, w[j * 3 + 0], bb[j])));
            o[j] = (__bf16)gelu_f(v);
        }
        *(bf16_8*)&h1[(size_t)n * 256 + c8 * 8] = o;
    }
}

// ---------------- mgemm (thin 128x128): used for g1d / g3 ----------------
template<int K, int GMODE, int WLD, int WOFF, bool BIAS, bool GELU_, bool FOURIER_,
         bool DADD_, bool POOL_, bool F32OUT>
__global__ __launch_bounds__(256, 3) void mgemm(
    const __bf16* __restrict__ Ag, const __bf16* __restrict__ h,
    const int* __restrict__ edges, const __bf16* __restrict__ W,
    const float* __restrict__ bias, __bf16* __restrict__ Cb,
    float* __restrict__ Cf, const __bf16* __restrict__ dmat,
    const float* __restrict__ pos, const float* __restrict__ bfour,
    int NB, int Nfull, int e0)
{
    __shared__ __align__(16) __bf16 sA[128 * 64];
    __shared__ __align__(16) __bf16 sB[128 * 64];
    __shared__ int s_idx[128];

    const int tid  = threadIdx.x;
    const int mblk = blockIdx.x / NB;
    const int nblk = blockIdx.x % NB;
    const int m0 = mblk * 128, n0 = nblk * 128;
    const int wave = tid >> 6, lane = tid & 63, ln = lane & 15, quad = lane >> 4;
    const int wm = wave >> 1, wn = wave & 1;

    if (GMODE) {
        if (tid < 128) {
            int r = m0 + tid;
            s_idx[tid] = (GMODE == 1) ? edges[2 * (e0 + r) + 1]
                                      : edges[2 * (DEG * r)];
        }
        __syncthreads();
    }

    const __bf16* pA[4];
    const __bf16* pB[4];
    #pragma unroll
    for (int i = 0; i < 4; i++) {
        int idx = i * 256 + tid;
        int row = idx >> 3, kg = (idx & 7) ^ (row & 7);
        pA[i] = GMODE ? h + (size_t)s_idx[row] * HID + kg * 8
                      : Ag + (size_t)(m0 + row) * K + kg * 8;
        pB[i] = W + (size_t)(n0 + row) * WLD + WOFF + kg * 8;
    }
    const int ach = quad ^ (ln & 7);
    const int aof[2] = { (wm * 64 + ln) * 64 + ach * 8, (wm * 64 + ln) * 64 + (ach ^ 4) * 8 };
    const int bof[2] = { (wn * 64 + ln) * 64 + ach * 8, (wn * 64 + ln) * 64 + (ach ^ 4) * 8 };

    f32_4 acc[4][4];
    #pragma unroll
    for (int i = 0; i < 4; i++)
        #pragma unroll
        for (int j = 0; j < 4; j++) acc[i][j] = zero4();

    bf16_8 ar[4], br[4];
    #pragma unroll
    for (int i = 0; i < 4; i++) {
        ar[i] = *(const bf16_8*)pA[i];
        br[i] = *(const bf16_8*)pB[i];
    }

    #pragma unroll
    for (int kb = 0; kb < K / 64; kb++) {
        if (kb > 0) __syncthreads();
        #pragma unroll
        for (int i = 0; i < 4; i++) {
            int idx = i * 256 + tid;
            *(bf16_8*)&sA[idx * 8] = ar[i];
            *(bf16_8*)&sB[idx * 8] = br[i];
        }
        __syncthreads();
        if (kb + 1 < K / 64) {
            #pragma unroll
            for (int i = 0; i < 4; i++) {
                ar[i] = *(const bf16_8*)(pA[i] + (kb + 1) * 64);
                br[i] = *(const bf16_8*)(pB[i] + (kb + 1) * 64);
            }
        }
        #pragma unroll
        for (int ks = 0; ks < 2; ks++) {
            bf16_8 af[4], bfr[4];
            #pragma unroll
            for (int mt = 0; mt < 4; mt++) af[mt]  = *(const bf16_8*)&sA[aof[ks] + mt * 1024];
            #pragma unroll
            for (int nt = 0; nt < 4; nt++) bfr[nt] = *(const bf16_8*)&sB[bof[ks] + nt * 1024];
            #pragma unroll
            for (int mt = 0; mt < 4; mt++)
                #pragma unroll
                for (int nt = 0; nt < 4; nt++)
                    acc[mt][nt] = __builtin_amdgcn_mfma_f32_16x16x32_bf16(af[mt], bfr[nt], acc[mt][nt], 0, 0, 0);
        }
    }

    if (POOL_) {
        #pragma unroll
        for (int nt = 0; nt < 4; nt++) {
            int col = n0 + wn * 64 + nt * 16 + ln;
            float bb = BIAS ? bias[col] : 0.f;
            #pragma unroll
            for (int mt = 0; mt < 4; mt++) {
                float s = gelu_f(acc[mt][nt][0] + bb) + gelu_f(acc[mt][nt][1] + bb)
                        + gelu_f(acc[mt][nt][2] + bb) + gelu_f(acc[mt][nt][3] + bb);
                s += __shfl_xor(s, 16);
                s += __shfl_xor(s, 32);
                if (quad == 0) {
                    int eg  = e0 + m0 + wm * 64 + mt * 16;
                    int dstn = edges[2 * eg];
                    Cb[(size_t)dstn * HID + col] = (__bf16)(s * 0.0625f);
                }
            }
        }
    } else if (F32OUT) {
        #pragma unroll
        for (int nt = 0; nt < 4; nt++) {
            int col = n0 + wn * 64 + nt * 16 + ln;
            float bb = BIAS ? bias[col] : 0.f;
            #pragma unroll
            for (int mt = 0; mt < 4; mt++) {
                #pragma unroll
                for (int r = 0; r < 4; r++) {
                    int rowE = m0 + wm * 64 + mt * 16 + quad * 4 + r;
                    Cf[(size_t)rowE * Nfull + col] = acc[mt][nt][r] + bb;
                }
            }
        }
    } else {
        __syncthreads();
        __bf16* sw = ((wave & 2) ? sB : sA) + (wave & 1) * 4096;
        const bool iscos = FOURIER_ && ((n0 + wn * 64) < 128);
        #pragma unroll
        for (int nt = 0; nt < 4; nt++) {
            int col = n0 + wn * 64 + nt * 16 + ln;
            float bb = BIAS ? bias[col] : 0.f;
            float Bc0 = 0.f, Bc1 = 0.f;
            if (FOURIER_) {
                int jm = col & 127;
                Bc0 = bfour[jm * 2 + 0];
                Bc1 = bfour[jm * 2 + 1];
            }
            #pragma unroll
            for (int mt = 0; mt < 4; mt++) {
                #pragma unroll
                for (int r = 0; r < 4; r++) {
                    int rowL = mt * 16 + quad * 4 + r;
                    float v = acc[mt][nt][r] + bb;
                    if (GELU_) v = gelu_f(v);
                    if (FOURIER_) {
                        int rowE = m0 + wm * 64 + rowL;
                        float f = 6.2831853071795864f *
                                  fmaf(pos[rowE * 2 + 1], Bc1, pos[rowE * 2 + 0] * Bc0);
                        v += iscos ? __cosf(f) : __sinf(f);
                    }
                    int colL = nt * 16 + ln;
                    sw[rowL * 64 + ((colL + rowL * 8) & 63)] = (__bf16)v;
                }
            }
        }
        __syncthreads();
        #pragma unroll
        for (int p = 0; p < 8; p++) {
            int rowL = p * 8 + (lane >> 3);
            int c8 = lane & 7;
            bf16_8 vv = *(const bf16_8*)&sw[rowL * 64 + ((c8 * 8 + rowL * 8) & 63)];
            int rowE = m0 + wm * 64 + rowL;
            if (DADD_) {
                int g = (e0 + rowE) >> 4;
                bf16_8 dd = *(const bf16_8*)&dmat[(size_t)g * 512 + n0 + wn * 64 + c8 * 8];
                #pragma unroll
                for (int j = 0; j < 8; j++)
                    vv[j] = (__bf16)gelu_f((float)vv[j] + (float)dd[j]);
            }
            *(bf16_8*)&Cb[(size_t)rowE * Nfull + n0 + wn * 64 + c8 * 8] = vv;
        }
    }
}

// ---------------- wgemm (wide 128x256): halves A staging traffic ----------------
// 4 waves 2x2, wave-tile 64x128, BK=64. A: register-prefetch dbuf (covers
// HBM/L3 gather latency with MFMA). B: global_load_lds DMA (L2-resident W,
// zero VGPR cost). acc[4][8]=128 VGPRs -> __launch_bounds__(256,2).
template<int K, int GMODE, int WLD, int WOFF, bool BIAS, bool GELU_, bool FOURIER_,
         bool DADD_, bool POOL_>
__global__ __launch_bounds__(256, 2) void wgemm(
    const __bf16* __restrict__ Ag, const __bf16* __restrict__ h,
    const int* __restrict__ edges, const __bf16* __restrict__ W,
    const float* __restrict__ bias, __bf16* __restrict__ Cb,
    const __bf16* __restrict__ dmat, const float* __restrict__ pos,
    const float* __restrict__ bfour, int NB, int Nfull, int e0)
{
    __shared__ __align__(16) __bf16 sA[128 * 64];   // 16 KB
    __shared__ __align__(16) __bf16 sB[256 * 64];   // 32 KB
    __shared__ int s_idx[128];

    const int tid  = threadIdx.x;
    const int mblk = blockIdx.x / NB;
    const int nblk = blockIdx.x % NB;
    const int m0 = mblk * 128, n0 = nblk * 256;
    const int wave = tid >> 6, lane = tid & 63, ln = lane & 15, quad = lane >> 4;
    const int wm = wave >> 1, wn = wave & 1;

    if (GMODE) {
        if (tid < 128) {
            int r = m0 + tid;
            s_idx[tid] = (GMODE == 1) ? edges[2 * (e0 + r) + 1]
                                      : edges[2 * (DEG * r)];
        }
        __syncthreads();
    }

    const __bf16* pA[4];
    const __bf16* pB[8];
    #pragma unroll
    for (int i = 0; i < 4; i++) {
        int idx = i * 256 + tid;
        int row = idx >> 3, kg = (idx & 7) ^ (row & 7);
        pA[i] = GMODE ? h + (size_t)s_idx[row] * HID + kg * 8
                      : Ag + (size_t)(m0 + row) * K + kg * 8;
    }
    #pragma unroll
    for (int i = 0; i < 8; i++) {
        int idx = i * 256 + tid;
        int row = idx >> 3, kg = (idx & 7) ^ (row & 7);
        pB[i] = W + (size_t)(n0 + row) * WLD + WOFF + kg * 8;
    }
    const int ach = quad ^ (ln & 7);
    const int aof[2] = { (wm * 64 + ln) * 64 + ach * 8, (wm * 64 + ln) * 64 + (ach ^ 4) * 8 };
    const int bof[2] = { (wn * 128 + ln) * 64 + ach * 8, (wn * 128 + ln) * 64 + (ach ^ 4) * 8 };

    f32_4 acc[4][8];
    #pragma unroll
    for (int i = 0; i < 4; i++)
        #pragma unroll
        for (int j = 0; j < 8; j++) acc[i][j] = zero4();

    bf16_8 ar[4];
    #pragma unroll
    for (int i = 0; i < 4; i++) ar[i] = *(const bf16_8*)pA[i];

    #pragma unroll
    for (int kb = 0; kb < K / 64; kb++) {
        if (kb > 0) __syncthreads();
        #pragma unroll
        for (int i = 0; i < 4; i++)
            *(bf16_8*)&sA[(i * 256 + tid) * 8] = ar[i];
        #pragma unroll
        for (int i = 0; i < 8; i++)
            load_lds16(pB[i] + kb * 64, &sB[(i * 256 + tid) * 8]);
        __syncthreads();               // drains B-DMA (L2 latency) + visibility
        if (kb + 1 < K / 64) {         // A prefetch in flight across MFMA below
            #pragma unroll
            for (int i = 0; i < 4; i++)
                ar[i] = *(const bf16_8*)(pA[i] + (kb + 1) * 64);
        }
        #pragma unroll
        for (int ks = 0; ks < 2; ks++) {
            bf16_8 af[4], bfr[8];
            #pragma unroll
            for (int mt = 0; mt < 4; mt++) af[mt]  = *(const bf16_8*)&sA[aof[ks] + mt * 1024];
            #pragma unroll
            for (int nt = 0; nt < 8; nt++) bfr[nt] = *(const bf16_8*)&sB[bof[ks] + nt * 1024];
            #pragma unroll
            for (int mt = 0; mt < 4; mt++)
                #pragma unroll
                for (int nt = 0; nt < 8; nt++)
                    acc[mt][nt] = __builtin_amdgcn_mfma_f32_16x16x32_bf16(af[mt], bfr[nt], acc[mt][nt], 0, 0, 0);
        }
    }

    if (POOL_) {
        #pragma unroll
        for (int nt = 0; nt < 8; nt++) {
            int col = n0 + wn * 128 + nt * 16 + ln;
            float bb = BIAS ? bias[col] : 0.f;
            #pragma unroll
            for (int mt = 0; mt < 4; mt++) {
                float s = gelu_f(acc[mt][nt][0] + bb) + gelu_f(acc[mt][nt][1] + bb)
                        + gelu_f(acc[mt][nt][2] + bb) + gelu_f(acc[mt][nt][3] + bb);
                s += __shfl_xor(s, 16);
                s += __shfl_xor(s, 32);
                if (quad == 0) {
                    int eg  = e0 + m0 + wm * 64 + mt * 16;
                    int dstn = edges[2 * eg];
                    Cb[(size_t)dstn * HID + col] = (__bf16)(s * 0.0625f);
                }
            }
        }
    } else {
        __syncthreads();               // all waves done reading sB fragments
        __bf16* sw = sB + wave * 4096; // per-wave 8 KB transpose region
        const bool iscos = FOURIER_ && ((n0 + wn * 128) < 128);
        #pragma unroll
        for (int half = 0; half < 2; half++) {
            #pragma unroll
            for (int ntl = 0; ntl < 4; ntl++) {
                int nt  = half * 4 + ntl;
                int col = n0 + wn * 128 + nt * 16 + ln;
                float bb = BIAS ? bias[col] : 0.f;
                float Bc0 = 0.f, Bc1 = 0.f;
                if (FOURIER_) {
                    int jm = col & 127;
                    Bc0 = bfour[jm * 2 + 0];
                    Bc1 = bfour[jm * 2 + 1];
                }
                #pragma unroll
                for (int mt = 0; mt < 4; mt++) {
                    #pragma unroll
                    for (int r = 0; r < 4; r++) {
                        int rowL = mt * 16 + quad * 4 + r;
                        float v = acc[mt][nt][r] + bb;
                        if (GELU_) v = gelu_f(v);
                        if (FOURIER_) {
                            int rowE = m0 + wm * 64 + rowL;
                            float f = 6.2831853071795864f *
                                      fmaf(pos[rowE * 2 + 1], Bc1, pos[rowE * 2 + 0] * Bc0);
                            v += iscos ? __cosf(f) : __sinf(f);
                        }
                        int colL = ntl * 16 + ln;
                        sw[rowL * 64 + ((colL + rowL * 8) & 63)] = (__bf16)v;
                    }
                }
            }
            // wave-private region: same-wave RAW ordering handled by lgkmcnt
            #pragma unroll
            for (int p = 0; p < 8; p++) {
                int rowL = p * 8 + (lane >> 3);
                int c8 = lane & 7;
                bf16_8 vv = *(const bf16_8*)&sw[rowL * 64 + ((c8 * 8 + rowL * 8) & 63)];
                int rowE = m0 + wm * 64 + rowL;
                int colg = n0 + wn * 128 + half * 64 + c8 * 8;
                if (DADD_) {
                    int g = (e0 + rowE) >> 4;
                    bf16_8 dd = *(const bf16_8*)&dmat[(size_t)g * 512 + colg];
                    #pragma unroll
                    for (int j = 0; j < 8; j++)
                        vv[j] = (__bf16)gelu_f((float)vv[j] + (float)dd[j]);
                }
                *(bf16_8*)&Cb[(size_t)rowE * Nfull + colg] = vv;
            }
        }
    }
}

extern "C" void kernel_launch(void* const* d_in, const int* in_sizes, int n_in,
                              void* d_out, int out_size, void* d_ws, size_t ws_size,
                              hipStream_t stream) {
    const float* x     = (const float*)d_in[0];
    const float* pos   = (const float*)d_in[1];
    const int*   edges = (const int*)d_in[2];
    const float* ip_w1 = (const float*)d_in[4];
    const float* ip_b1 = (const float*)d_in[5];
    const float* ip_w2 = (const float*)d_in[6];
    const float* ip_b2 = (const float*)d_in[7];
    const float* ip_w3 = (const float*)d_in[8];
    const float* ip_b3 = (const float*)d_in[9];
    const float* bfour = (const float*)d_in[10];
    const float* mw1   = (const float*)d_in[11];
    const float* mb1   = (const float*)d_in[12];
    const float* mw2   = (const float*)d_in[13];
    const float* mb2   = (const float*)d_in[14];
    const float* mw3   = (const float*)d_in[15];
    const float* mb3   = (const float*)d_in[16];

    char* ws = (char*)d_ws;
    __bf16* hA = (__bf16*)ws;                                // 64 MB: h1 / final h
    __bf16* hB = hA + (size_t)N_NODES * HID;                 // 64 MB: h2 temp
    size_t off = (size_t)N_NODES * HID * 2 * 2;
    __bf16* wb = (__bf16*)(ws + off);                        // 1.125 MB bf16 weights
    off += (size_t)589824 * 2;
    off = (off + 255) & ~(size_t)255;
    __bf16* dbuf = (__bf16*)(ws + off);                      // 16 MB: d = h_dst @ W1b^T
    off += (size_t)N_DST * 512 * 2;
    __bf16* p2 = (__bf16*)(ws + off);                        // 8 MB: pooled m2
    off += (size_t)N_DST * HID * 2;
    off = (off + 255) & ~(size_t)255;
    char* scratch = ws + off;
    size_t avail = ws_size > off ? ws_size - off : 0;

    // chunk edges so m1 (eC*512 bf16) fits in remaining workspace
    int C = 1;
    while (C < 16 && ((size_t)N_EDGES / C) * 512 * 2 > avail) C <<= 1;
    const int eC  = N_EDGES / C;
    const int mbC = eC / 128;

    __bf16* w2b  = wb;
    __bf16* w3b  = wb + 65536;
    __bf16* mw1b = wb + 131072;
    __bf16* mw2b = wb + 393216;
    __bf16* mw3b = wb + 524288;
    __bf16* m1c  = (__bf16*)scratch;

    prep_kernel<<<2304, 256, 0, stream>>>(wb, ip_w2, ip_w3, mw1, mw2, mw3);

    // encoder: h1 -> hA; h2 -> hB; h (fourier) -> hA
    enc1_kernel<<<2048, 256, 0, stream>>>(x, ip_w1, ip_b1, hA);
    wgemm<256, 0, 256, 0, true, true,  false, false, false><<<1024, 256, 0, stream>>>(
        hA, nullptr, nullptr, w2b, ip_b2, hB, nullptr, nullptr, nullptr, 1, 256, 0);
    wgemm<256, 0, 256, 0, true, false, true,  false, false><<<1024, 256, 0, stream>>>(
        hB, nullptr, nullptr, w3b, ip_b3, hA, nullptr, pos, bfour, 1, 256, 0);

    // d[g] = h[dst(g)] @ W1b^T  (16384 x 512, K=256) -- thin kernel
    mgemm<256, 2, 512, 256, false, false, false, false, false, false><<<512, 256, 0, stream>>>(
        nullptr, hA, edges, mw1b, nullptr, dbuf, nullptr, nullptr, nullptr, nullptr, 4, 512, 0);

    for (int c = 0; c < C; c++) {
        int e0 = c * eC;
        // m1 = gelu(h[src] @ W1a^T + b1 + d[e>>4])  (eC x 512, K=256), NB=2
        wgemm<256, 1, 512, 0, true, false, false, true, false><<<mbC * 2, 256, 0, stream>>>(
            nullptr, hA, edges, mw1b, mb1, m1c, dbuf, nullptr, nullptr, 2, 512, e0);
        // p2[dst] = mean_group(gelu(m1 @ W2^T + b2))  (pool fused; K=512), NB=1
        wgemm<512, 0, 512, 0, true, false, false, false, true ><<<mbC, 256, 0, stream>>>(
            m1c, nullptr, edges, mw2b, mb2, p2, nullptr, nullptr, nullptr, 1, 256, e0);
    }
    // out = p2 @ W3^T + b3  (16384 x 256, K=256), fp32 -- thin kernel
    mgemm<256, 0, 256, 0, true, false, false, false, false, true><<<256, 256, 0, stream>>>(
        p2, nullptr, nullptr, mw3b, mb3, nullptr, (float*)d_out, nullptr, nullptr, nullptr, 2, 256, 0);
}

// Round 10
// 559.023 us; speedup vs baseline: 1.4685x; 1.0244x over previous
//
#include <hip/hip_runtime.h>
#include <math.h>

#define N_NODES 131072
#define N_DST   16384
#define DEG     16
#define HID     256
#define N_EDGES 262144

typedef __bf16 bf16_8 __attribute__((ext_vector_type(8)));
typedef float  f32_4  __attribute__((ext_vector_type(4)));

// tanh-approx gelu via hardware v_exp_f32: |err| <~1e-3, threshold is 2.2e-2
__device__ __forceinline__ float gelu_f(float v) {
    float t = 1.5957691216f * fmaf(v * v, 0.044715f * v, v);
    return v / (1.0f + __expf(-t));
}
__device__ __forceinline__ f32_4 zero4() {
    f32_4 z; z[0] = 0.f; z[1] = 0.f; z[2] = 0.f; z[3] = 0.f; return z;
}

// async global->LDS, 16B per lane. LDS side must be wave-uniform base + lane*16.
__device__ __forceinline__ void load_lds16(const __bf16* g, __bf16* l) {
    __builtin_amdgcn_global_load_lds(
        (__attribute__((address_space(1))) void*)g,
        (__attribute__((address_space(3))) void*)l, 16, 0, 0);
}

// ---------------- prep: fp32 -> bf16 weights ----------------
__global__ void prep_kernel(__bf16* __restrict__ out,
                            const float* __restrict__ w2,
                            const float* __restrict__ w3,
                            const float* __restrict__ mw1,
                            const float* __restrict__ mw2,
                            const float* __restrict__ mw3) {
    int stride = gridDim.x * blockDim.x;
    for (int i = blockIdx.x * blockDim.x + threadIdx.x; i < 589824; i += stride) {
        float v;
        if      (i <  65536) v = w2[i];
        else if (i < 131072) v = w3[i - 65536];
        else if (i < 393216) v = mw1[i - 131072];
        else if (i < 524288) v = mw2[i - 393216];
        else                 v = mw3[i - 524288];
        out[i] = (__bf16)v;
    }
}

// ---------------- encoder layer 1 (K=3): weights in registers, grid-stride ----
__global__ __launch_bounds__(256) void enc1_kernel(
    const float* __restrict__ x, const float* __restrict__ w1,
    const float* __restrict__ b1, __bf16* __restrict__ h1) {
    const int c8   = threadIdx.x & 31;
    const int nloc = threadIdx.x >> 5;
    float w[24], bb[8];
    #pragma unroll
    for (int i = 0; i < 6; i++) *(float4*)&w[i * 4] = ((const float4*)w1)[c8 * 6 + i];
    *(float4*)&bb[0] = ((const float4*)b1)[c8 * 2 + 0];
    *(float4*)&bb[4] = ((const float4*)b1)[c8 * 2 + 1];
    for (int n = blockIdx.x * 8 + nloc; n < N_NODES; n += gridDim.x * 8) {
        float x0 = x[n * 3 + 0], x1 = x[n * 3 + 1], x2 = x[n * 3 + 2];
        bf16_8 o;
        #pragma unroll
        for (int j = 0; j < 8; j++) {
            float v = fmaf(x2, w[j * 3 + 2],
                      fmaf(x1, w[j * 3 + 1],
                      fmaf(x0, w[j * 3 + 0], bb[j])));
            o[j] = (__bf16)gelu_f(v);
        }
        *(bf16_8*)&h1[(size_t)n * 256 + c8 * 8] = o;
    }
}

// ---------------- mgemm (thin 128x128): used for g1d / g3 ----------------
template<int K, int GMODE, int WLD, int WOFF, bool BIAS, bool GELU_, bool FOURIER_,
         bool DADD_, bool POOL_, bool F32OUT>
__global__ __launch_bounds__(256, 3) void mgemm(
    const __bf16* __restrict__ Ag, const __bf16* __restrict__ h,
    const int* __restrict__ edges, const __bf16* __restrict__ W,
    const float* __restrict__ bias, __bf16* __restrict__ Cb,
    float* __restrict__ Cf, const __bf16* __restrict__ dmat,
    const float* __restrict__ pos, const float* __restrict__ bfour,
    int NB, int Nfull, int e0)
{
    __shared__ __align__(16) __bf16 sA[128 * 64];
    __shared__ __align__(16) __bf16 sB[128 * 64];
    __shared__ int s_idx[128];

    const int tid  = threadIdx.x;
    const int mblk = blockIdx.x / NB;
    const int nblk = blockIdx.x % NB;
    const int m0 = mblk * 128, n0 = nblk * 128;
    const int wave = tid >> 6, lane = tid & 63, ln = lane & 15, quad = lane >> 4;
    const int wm = wave >> 1, wn = wave & 1;

    if (GMODE) {
        if (tid < 128) {
            int r = m0 + tid;
            s_idx[tid] = (GMODE == 1) ? edges[2 * (e0 + r) + 1]
                                      : edges[2 * (DEG * r)];
        }
        __syncthreads();
    }

    const __bf16* pA[4];
    const __bf16* pB[4];
    #pragma unroll
    for (int i = 0; i < 4; i++) {
        int idx = i * 256 + tid;
        int row = idx >> 3, kg = (idx & 7) ^ (row & 7);
        pA[i] = GMODE ? h + (size_t)s_idx[row] * HID + kg * 8
                      : Ag + (size_t)(m0 + row) * K + kg * 8;
        pB[i] = W + (size_t)(n0 + row) * WLD + WOFF + kg * 8;
    }
    const int ach = quad ^ (ln & 7);
    const int aof[2] = { (wm * 64 + ln) * 64 + ach * 8, (wm * 64 + ln) * 64 + (ach ^ 4) * 8 };
    const int bof[2] = { (wn * 64 + ln) * 64 + ach * 8, (wn * 64 + ln) * 64 + (ach ^ 4) * 8 };

    f32_4 acc[4][4];
    #pragma unroll
    for (int i = 0; i < 4; i++)
        #pragma unroll
        for (int j = 0; j < 4; j++) acc[i][j] = zero4();

    bf16_8 ar[4], br[4];
    #pragma unroll
    for (int i = 0; i < 4; i++) {
        ar[i] = *(const bf16_8*)pA[i];
        br[i] = *(const bf16_8*)pB[i];
    }

    #pragma unroll
    for (int kb = 0; kb < K / 64; kb++) {
        if (kb > 0) __syncthreads();
        #pragma unroll
        for (int i = 0; i < 4; i++) {
            int idx = i * 256 + tid;
            *(bf16_8*)&sA[idx * 8] = ar[i];
            *(bf16_8*)&sB[idx * 8] = br[i];
        }
        __syncthreads();
        if (kb + 1 < K / 64) {
            #pragma unroll
            for (int i = 0; i < 4; i++) {
                ar[i] = *(const bf16_8*)(pA[i] + (kb + 1) * 64);
                br[i] = *(const bf16_8*)(pB[i] + (kb + 1) * 64);
            }
        }
        #pragma unroll
        for (int ks = 0; ks < 2; ks++) {
            bf16_8 af[4], bfr[4];
            #pragma unroll
            for (int mt = 0; mt < 4; mt++) af[mt]  = *(const bf16_8*)&sA[aof[ks] + mt * 1024];
            #pragma unroll
            for (int nt = 0; nt < 4; nt++) bfr[nt] = *(const bf16_8*)&sB[bof[ks] + nt * 1024];
            #pragma unroll
            for (int mt = 0; mt < 4; mt++)
                #pragma unroll
                for (int nt = 0; nt < 4; nt++)
                    acc[mt][nt] = __builtin_amdgcn_mfma_f32_16x16x32_bf16(af[mt], bfr[nt], acc[mt][nt], 0, 0, 0);
        }
    }

    if (POOL_) {
        #pragma unroll
        for (int nt = 0; nt < 4; nt++) {
            int col = n0 + wn * 64 + nt * 16 + ln;
            float bb = BIAS ? bias[col] : 0.f;
            #pragma unroll
            for (int mt = 0; mt < 4; mt++) {
                float s = gelu_f(acc[mt][nt][0] + bb) + gelu_f(acc[mt][nt][1] + bb)
                        + gelu_f(acc[mt][nt][2] + bb) + gelu_f(acc[mt][nt][3] + bb);
                s += __shfl_xor(s, 16);
                s += __shfl_xor(s, 32);
                if (quad == 0) {
                    int eg  = e0 + m0 + wm * 64 + mt * 16;
                    int dstn = edges[2 * eg];
                    Cb[(size_t)dstn * HID + col] = (__bf16)(s * 0.0625f);
                }
            }
        }
    } else if (F32OUT) {
        #pragma unroll
        for (int nt = 0; nt < 4; nt++) {
            int col = n0 + wn * 64 + nt * 16 + ln;
            float bb = BIAS ? bias[col] : 0.f;
            #pragma unroll
            for (int mt = 0; mt < 4; mt++) {
                #pragma unroll
                for (int r = 0; r < 4; r++) {
                    int rowE = m0 + wm * 64 + mt * 16 + quad * 4 + r;
                    Cf[(size_t)rowE * Nfull + col] = acc[mt][nt][r] + bb;
                }
            }
        }
    } else {
        __syncthreads();
        __bf16* sw = ((wave & 2) ? sB : sA) + (wave & 1) * 4096;
        const bool iscos = FOURIER_ && ((n0 + wn * 64) < 128);
        #pragma unroll
        for (int nt = 0; nt < 4; nt++) {
            int col = n0 + wn * 64 + nt * 16 + ln;
            float bb = BIAS ? bias[col] : 0.f;
            float Bc0 = 0.f, Bc1 = 0.f;
            if (FOURIER_) {
                int jm = col & 127;
                Bc0 = bfour[jm * 2 + 0];
                Bc1 = bfour[jm * 2 + 1];
            }
            #pragma unroll
            for (int mt = 0; mt < 4; mt++) {
                #pragma unroll
                for (int r = 0; r < 4; r++) {
                    int rowL = mt * 16 + quad * 4 + r;
                    float v = acc[mt][nt][r] + bb;
                    if (GELU_) v = gelu_f(v);
                    if (FOURIER_) {
                        int rowE = m0 + wm * 64 + rowL;
                        float f = 6.2831853071795864f *
                                  fmaf(pos[rowE * 2 + 1], Bc1, pos[rowE * 2 + 0] * Bc0);
                        v += iscos ? __cosf(f) : __sinf(f);
                    }
                    int colL = nt * 16 + ln;
                    sw[rowL * 64 + ((colL + rowL * 8) & 63)] = (__bf16)v;
                }
            }
        }
        __syncthreads();
        #pragma unroll
        for (int p = 0; p < 8; p++) {
            int rowL = p * 8 + (lane >> 3);
            int c8 = lane & 7;
            bf16_8 vv = *(const bf16_8*)&sw[rowL * 64 + ((c8 * 8 + rowL * 8) & 63)];
            int rowE = m0 + wm * 64 + rowL;
            if (DADD_) {
                int g = (e0 + rowE) >> 4;
                bf16_8 dd = *(const bf16_8*)&dmat[(size_t)g * 512 + n0 + wn * 64 + c8 * 8];
                #pragma unroll
                for (int j = 0; j < 8; j++)
                    vv[j] = (__bf16)gelu_f((float)vv[j] + (float)dd[j]);
            }
            *(bf16_8*)&Cb[(size_t)rowE * Nfull + n0 + wn * 64 + c8 * 8] = vv;
        }
    }
}

// ---------------- wgemm (wide 128x256) ----------------
template<int K, int GMODE, int WLD, int WOFF, bool BIAS, bool GELU_, bool FOURIER_,
         bool DADD_, bool POOL_>
__global__ __launch_bounds__(256, 2) void wgemm(
    const __bf16* __restrict__ Ag, const __bf16* __restrict__ h,
    const int* __restrict__ edges, const __bf16* __restrict__ W,
    const float* __restrict__ bias, __bf16* __restrict__ Cb,
    const __bf16* __restrict__ dmat, const float* __restrict__ pos,
    const float* __restrict__ bfour, int NB, int Nfull, int e0)
{
    __shared__ __align__(16) __bf16 sA[128 * 64];   // 16 KB
    __shared__ __align__(16) __bf16 sB[256 * 64];   // 32 KB
    __shared__ int s_idx[128];

    const int tid  = threadIdx.x;
    const int mblk = blockIdx.x / NB;
    const int nblk = blockIdx.x % NB;
    const int m0 = mblk * 128, n0 = nblk * 256;
    const int wave = tid >> 6, lane = tid & 63, ln = lane & 15, quad = lane >> 4;
    const int wm = wave >> 1, wn = wave & 1;

    if (GMODE) {
        if (tid < 128) {
            int r = m0 + tid;
            s_idx[tid] = (GMODE == 1) ? edges[2 * (e0 + r) + 1]
                                      : edges[2 * (DEG * r)];
        }
        __syncthreads();
    }

    const __bf16* pA[4];
    const __bf16* pB[8];
    #pragma unroll
    for (int i = 0; i < 4; i++) {
        int idx = i * 256 + tid;
        int row = idx >> 3, kg = (idx & 7) ^ (row & 7);
        pA[i] = GMODE ? h + (size_t)s_idx[row] * HID + kg * 8
                      : Ag + (size_t)(m0 + row) * K + kg * 8;
    }
    #pragma unroll
    for (int i = 0; i < 8; i++) {
        int idx = i * 256 + tid;
        int row = idx >> 3, kg = (idx & 7) ^ (row & 7);
        pB[i] = W + (size_t)(n0 + row) * WLD + WOFF + kg * 8;
    }
    const int ach = quad ^ (ln & 7);
    const int aof[2] = { (wm * 64 + ln) * 64 + ach * 8, (wm * 64 + ln) * 64 + (ach ^ 4) * 8 };
    const int bof[2] = { (wn * 128 + ln) * 64 + ach * 8, (wn * 128 + ln) * 64 + (ach ^ 4) * 8 };

    f32_4 acc[4][8];
    #pragma unroll
    for (int i = 0; i < 4; i++)
        #pragma unroll
        for (int j = 0; j < 8; j++) acc[i][j] = zero4();

    bf16_8 ar[4];
    #pragma unroll
    for (int i = 0; i < 4; i++) ar[i] = *(const bf16_8*)pA[i];

    #pragma unroll
    for (int kb = 0; kb < K / 64; kb++) {
        if (kb > 0) __syncthreads();
        #pragma unroll
        for (int i = 0; i < 4; i++)
            *(bf16_8*)&sA[(i * 256 + tid) * 8] = ar[i];
        #pragma unroll
        for (int i = 0; i < 8; i++)
            load_lds16(pB[i] + kb * 64, &sB[(i * 256 + tid) * 8]);
        __syncthreads();
        if (kb + 1 < K / 64) {
            #pragma unroll
            for (int i = 0; i < 4; i++)
                ar[i] = *(const bf16_8*)(pA[i] + (kb + 1) * 64);
        }
        #pragma unroll
        for (int ks = 0; ks < 2; ks++) {
            bf16_8 af[4], bfr[8];
            #pragma unroll
            for (int mt = 0; mt < 4; mt++) af[mt]  = *(const bf16_8*)&sA[aof[ks] + mt * 1024];
            #pragma unroll
            for (int nt = 0; nt < 8; nt++) bfr[nt] = *(const bf16_8*)&sB[bof[ks] + nt * 1024];
            #pragma unroll
            for (int mt = 0; mt < 4; mt++)
                #pragma unroll
                for (int nt = 0; nt < 8; nt++)
                    acc[mt][nt] = __builtin_amdgcn_mfma_f32_16x16x32_bf16(af[mt], bfr[nt], acc[mt][nt], 0, 0, 0);
        }
    }

    if (POOL_) {
        #pragma unroll
        for (int nt = 0; nt < 8; nt++) {
            int col = n0 + wn * 128 + nt * 16 + ln;
            float bb = BIAS ? bias[col] : 0.f;
            #pragma unroll
            for (int mt = 0; mt < 4; mt++) {
                float s = gelu_f(acc[mt][nt][0] + bb) + gelu_f(acc[mt][nt][1] + bb)
                        + gelu_f(acc[mt][nt][2] + bb) + gelu_f(acc[mt][nt][3] + bb);
                s += __shfl_xor(s, 16);
                s += __shfl_xor(s, 32);
                if (quad == 0) {
                    int eg  = e0 + m0 + wm * 64 + mt * 16;
                    int dstn = edges[2 * eg];
                    Cb[(size_t)dstn * HID + col] = (__bf16)(s * 0.0625f);
                }
            }
        }
    } else {
        __syncthreads();
        __bf16* sw = sB + wave * 4096;
        const bool iscos = FOURIER_ && ((n0 + wn * 128) < 128);
        #pragma unroll
        for (int half = 0; half < 2; half++) {
            #pragma unroll
            for (int ntl = 0; ntl < 4; ntl++) {
                int nt  = half * 4 + ntl;
                int col = n0 + wn * 128 + nt * 16 + ln;
                float bb = BIAS ? bias[col] : 0.f;
                float Bc0 = 0.f, Bc1 = 0.f;
                if (FOURIER_) {
                    int jm = col & 127;
                    Bc0 = bfour[jm * 2 + 0];
                    Bc1 = bfour[jm * 2 + 1];
                }
                #pragma unroll
                for (int mt = 0; mt < 4; mt++) {
                    #pragma unroll
                    for (int r = 0; r < 4; r++) {
                        int rowL = mt * 16 + quad * 4 + r;
                        float v = acc[mt][nt][r] + bb;
                        if (GELU_) v = gelu_f(v);
                        if (FOURIER_) {
                            int rowE = m0 + wm * 64 + rowL;
                            float f = 6.2831853071795864f *
                                      fmaf(pos[rowE * 2 + 1], Bc1, pos[rowE * 2 + 0] * Bc0);
                            v += iscos ? __cosf(f) : __sinf(f);
                        }
                        int colL = ntl * 16 + ln;
                        sw[rowL * 64 + ((colL + rowL * 8) & 63)] = (__bf16)v;
                    }
                }
            }
            #pragma unroll
            for (int p = 0; p < 8; p++) {
                int rowL = p * 8 + (lane >> 3);
                int c8 = lane & 7;
                bf16_8 vv = *(const bf16_8*)&sw[rowL * 64 + ((c8 * 8 + rowL * 8) & 63)];
                int rowE = m0 + wm * 64 + rowL;
                int colg = n0 + wn * 128 + half * 64 + c8 * 8;
                if (DADD_) {
                    int g = (e0 + rowE) >> 4;
                    bf16_8 dd = *(const bf16_8*)&dmat[(size_t)g * 512 + colg];
                    #pragma unroll
                    for (int j = 0; j < 8; j++)
                        vv[j] = (__bf16)gelu_f((float)vv[j] + (float)dd[j]);
                }
                *(bf16_8*)&Cb[(size_t)rowE * Nfull + colg] = vv;
            }
        }
    }
}

extern "C" void kernel_launch(void* const* d_in, const int* in_sizes, int n_in,
                              void* d_out, int out_size, void* d_ws, size_t ws_size,
                              hipStream_t stream) {
    const float* x     = (const float*)d_in[0];
    const float* pos   = (const float*)d_in[1];
    const int*   edges = (const int*)d_in[2];
    const float* ip_w1 = (const float*)d_in[4];
    const float* ip_b1 = (const float*)d_in[5];
    const float* ip_w2 = (const float*)d_in[6];
    const float* ip_b2 = (const float*)d_in[7];
    const float* ip_w3 = (const float*)d_in[8];
    const float* ip_b3 = (const float*)d_in[9];
    const float* bfour = (const float*)d_in[10];
    const float* mw1   = (const float*)d_in[11];
    const float* mb1   = (const float*)d_in[12];
    const float* mw2   = (const float*)d_in[13];
    const float* mb2   = (const float*)d_in[14];
    const float* mw3   = (const float*)d_in[15];
    const float* mb3   = (const float*)d_in[16];

    // L3-residency layout (total ~153 MB < 256 MB Infinity Cache):
    //   hA 64 MB (h1 / final h) | hB 64 MB (h2 temp, ALIASED as m1 chunk buffer
    //   after encL3 consumes it) | weights 1.125 MB | dbuf 16 MB | p2 8 MB.
    // Keeping the whole working set under L3 capacity is what keeps the random
    // h-row gather an L3 hit instead of an HBM random-access miss (R9 lesson).
    char* ws = (char*)d_ws;
    __bf16* hA = (__bf16*)ws;
    __bf16* hB = hA + (size_t)N_NODES * HID;
    size_t off = (size_t)N_NODES * HID * 2 * 2;
    __bf16* wb = (__bf16*)(ws + off);
    off += (size_t)589824 * 2;
    off = (off + 255) & ~(size_t)255;
    __bf16* dbuf = (__bf16*)(ws + off);                      // 16 MB: d = h_dst @ W1b^T
    off += (size_t)N_DST * 512 * 2;
    __bf16* p2 = (__bf16*)(ws + off);                        // 8 MB: pooled m2
    off += (size_t)N_DST * HID * 2;

    const int C   = 4;                 // eC*512*2 = 64 MiB = hB size exactly
    const int eC  = N_EDGES / C;       // 65536 edges per chunk
    const int mbC = eC / 128;          // 512 M-blocks per chunk

    __bf16* w2b  = wb;
    __bf16* w3b  = wb + 65536;
    __bf16* mw1b = wb + 131072;
    __bf16* mw2b = wb + 393216;
    __bf16* mw3b = wb + 524288;
    __bf16* m1c  = hB;                 // alias: hB is dead after encL3

    prep_kernel<<<2304, 256, 0, stream>>>(wb, ip_w2, ip_w3, mw1, mw2, mw3);

    // encoder: h1 -> hA; h2 -> hB; h (fourier) -> hA
    enc1_kernel<<<2048, 256, 0, stream>>>(x, ip_w1, ip_b1, hA);
    wgemm<256, 0, 256, 0, true, true,  false, false, false><<<1024, 256, 0, stream>>>(
        hA, nullptr, nullptr, w2b, ip_b2, hB, nullptr, nullptr, nullptr, 1, 256, 0);
    wgemm<256, 0, 256, 0, true, false, true,  false, false><<<1024, 256, 0, stream>>>(
        hB, nullptr, nullptr, w3b, ip_b3, hA, nullptr, pos, bfour, 1, 256, 0);

    // d[g] = h[dst(g)] @ W1b^T  (16384 x 512, K=256) -- thin kernel
    mgemm<256, 2, 512, 256, false, false, false, false, false, false><<<512, 256, 0, stream>>>(
        nullptr, hA, edges, mw1b, nullptr, dbuf, nullptr, nullptr, nullptr, nullptr, 4, 512, 0);

    for (int c = 0; c < C; c++) {
        int e0 = c * eC;
        // m1 = gelu(h[src] @ W1a^T + b1 + d[e>>4])  (eC x 512, K=256), NB=2
        wgemm<256, 1, 512, 0, true, false, false, true, false><<<mbC * 2, 256, 0, stream>>>(
            nullptr, hA, edges, mw1b, mb1, m1c, dbuf, nullptr, nullptr, 2, 512, e0);
        // p2[dst] = mean_group(gelu(m1 @ W2^T + b2))  (pool fused; K=512), NB=1
        wgemm<512, 0, 512, 0, true, false, false, false, true ><<<mbC, 256, 0, stream>>>(
            m1c, nullptr, edges, mw2b, mb2, p2, nullptr, nullptr, nullptr, 1, 256, e0);
    }
    // out = p2 @ W3^T + b3  (16384 x 256, K=256), fp32 -- thin kernel
    mgemm<256, 0, 256, 0, true, false, false, false, false, true><<<256, 256, 0, stream>>>(
        p2, nullptr, nullptr, mw3b, mb3, nullptr, (float*)d_out, nullptr, nullptr, nullptr, 2, 256, 0);
}

// Round 11
// 488.997 us; speedup vs baseline: 1.6788x; 1.1432x over previous
//
#include <hip/hip_runtime.h>
#include <math.h>

#define N_NODES 131072
#define N_DST   16384
#define DEG     16
#define HID     256
#define N_EDGES 262144

typedef __bf16 bf16_8 __attribute__((ext_vector_type(8)));
typedef float  f32_4  __attribute__((ext_vector_type(4)));

// tanh-approx gelu via hardware v_exp_f32: |err| <~1e-3, threshold is 2.2e-2
__device__ __forceinline__ float gelu_f(float v) {
    float t = 1.5957691216f * fmaf(v * v, 0.044715f * v, v);
    return v / (1.0f + __expf(-t));
}
__device__ __forceinline__ f32_4 zero4() {
    f32_4 z; z[0] = 0.f; z[1] = 0.f; z[2] = 0.f; z[3] = 0.f; return z;
}

// async global->LDS, 16B per lane. LDS side must be wave-uniform base + lane*16.
__device__ __forceinline__ void load_lds16(const __bf16* g, __bf16* l) {
    __builtin_amdgcn_global_load_lds(
        (__attribute__((address_space(1))) void*)g,
        (__attribute__((address_space(3))) void*)l, 16, 0, 0);
}

// ---------------- prep: fp32 -> bf16 weights ----------------
__global__ void prep_kernel(__bf16* __restrict__ out,
                            const float* __restrict__ w2,
                            const float* __restrict__ w3,
                            const float* __restrict__ mw1,
                            const float* __restrict__ mw2,
                            const float* __restrict__ mw3) {
    int stride = gridDim.x * blockDim.x;
    for (int i = blockIdx.x * blockDim.x + threadIdx.x; i < 589824; i += stride) {
        float v;
        if      (i <  65536) v = w2[i];
        else if (i < 131072) v = w3[i - 65536];
        else if (i < 393216) v = mw1[i - 131072];
        else if (i < 524288) v = mw2[i - 393216];
        else                 v = mw3[i - 524288];
        out[i] = (__bf16)v;
    }
}

// ---------------- encoder layer 1 (K=3): weights in registers, grid-stride ----
__global__ __launch_bounds__(256) void enc1_kernel(
    const float* __restrict__ x, const float* __restrict__ w1,
    const float* __restrict__ b1, __bf16* __restrict__ h1) {
    const int c8   = threadIdx.x & 31;
    const int nloc = threadIdx.x >> 5;
    float w[24], bb[8];
    #pragma unroll
    for (int i = 0; i < 6; i++) *(float4*)&w[i * 4] = ((const float4*)w1)[c8 * 6 + i];
    *(float4*)&bb[0] = ((const float4*)b1)[c8 * 2 + 0];
    *(float4*)&bb[4] = ((const float4*)b1)[c8 * 2 + 1];
    for (int n = blockIdx.x * 8 + nloc; n < N_NODES; n += gridDim.x * 8) {
        float x0 = x[n * 3 + 0], x1 = x[n * 3 + 1], x2 = x[n * 3 + 2];
        bf16_8 o;
        #pragma unroll
        for (int j = 0; j < 8; j++) {
            float v = fmaf(x2, w[j * 3 + 2],
                      fmaf(x1, w[j * 3 + 1],
                      fmaf(x0, w[j * 3 + 0], bb[j])));
            o[j] = (__bf16)gelu_f(v);
        }
        *(bf16_8*)&h1[(size_t)n * 256 + c8 * 8] = o;
    }
}

// ---------------- enc23: fused encoder L2+L3, in-place on hA ----------------
// 64 rows/block; waves 2x2 -> wave tile 32x128; h2 (64x256) stays in LDS.
__global__ __launch_bounds__(256, 2) void enc23_kernel(
    __bf16* __restrict__ hA,
    const __bf16* __restrict__ W2, const float* __restrict__ b2,
    const __bf16* __restrict__ W3, const float* __restrict__ b3,
    const float* __restrict__ pos, const float* __restrict__ bfour)
{
    __shared__ __align__(16) __bf16 sA[64 * 64];     // 8 KB input slab
    __shared__ __align__(16) __bf16 sB[16384];       // 32 KB W slab / epi transpose
    __shared__ __align__(16) __bf16 sH2[64 * 256];   // 32 KB h2 (A-layout)

    const int tid = threadIdx.x;
    const int m0  = blockIdx.x * 64;
    const int wave = tid >> 6, lane = tid & 63, ln = lane & 15, quad = lane >> 4;
    const int wm = wave >> 1, wn = wave & 1;

    // A base pointers (2 slots/thread)
    const __bf16* pA[2];
    #pragma unroll
    for (int i = 0; i < 2; i++) {
        int idx = i * 256 + tid;
        int row = idx >> 3, kg = (idx & 7) ^ (row & 7);
        pA[i] = hA + (size_t)(m0 + row) * 256 + kg * 8;
    }

    f32_4 acc[2][8];
    #pragma unroll
    for (int i = 0; i < 2; i++)
        #pragma unroll
        for (int j = 0; j < 8; j++) acc[i][j] = zero4();

    bf16_8 ar[2];
    #pragma unroll
    for (int i = 0; i < 2; i++) ar[i] = *(const bf16_8*)pA[i];

    // ---- phase 1: h2 = gelu(h1 @ W2^T + b2) ----
    #pragma unroll
    for (int kb = 0; kb < 4; kb++) {
        if (kb > 0) __syncthreads();
        #pragma unroll
        for (int i = 0; i < 2; i++)
            *(bf16_8*)&sA[(i * 256 + tid) * 8] = ar[i];
        #pragma unroll
        for (int i = 0; i < 8; i++) {
            int idx = i * 256 + tid;
            int row = idx >> 3, kg = (idx & 7) ^ (row & 7);
            load_lds16(W2 + (size_t)row * 256 + kb * 64 + kg * 8, &sB[idx * 8]);
        }
        __syncthreads();
        if (kb < 3) {
            #pragma unroll
            for (int i = 0; i < 2; i++)
                ar[i] = *(const bf16_8*)(pA[i] + (kb + 1) * 64);
        }
        #pragma unroll
        for (int ks = 0; ks < 2; ks++) {
            int c = ks * 4 + quad;
            bf16_8 af[2], bfr[8];
            #pragma unroll
            for (int mt = 0; mt < 2; mt++) {
                int mr = wm * 32 + mt * 16 + ln;
                af[mt] = *(const bf16_8*)&sA[mr * 64 + (c ^ (mr & 7)) * 8];
            }
            #pragma unroll
            for (int nt = 0; nt < 8; nt++) {
                int nr = wn * 128 + nt * 16 + ln;
                bfr[nt] = *(const bf16_8*)&sB[nr * 64 + (c ^ (nr & 7)) * 8];
            }
            #pragma unroll
            for (int mt = 0; mt < 2; mt++)
                #pragma unroll
                for (int nt = 0; nt < 8; nt++)
                    acc[mt][nt] = __builtin_amdgcn_mfma_f32_16x16x32_bf16(af[mt], bfr[nt], acc[mt][nt], 0, 0, 0);
        }
    }
    // epi1 -> sH2 (add-rotation swizzle, keeps 8-elem contiguity)
    #pragma unroll
    for (int nt = 0; nt < 8; nt++) {
        int col = wn * 128 + nt * 16 + ln;
        float bb = b2[col];
        #pragma unroll
        for (int mt = 0; mt < 2; mt++) {
            #pragma unroll
            for (int r = 0; r < 4; r++) {
                int row = wm * 32 + mt * 16 + quad * 4 + r;
                sH2[row * 256 + ((col + row * 8) & 255)] = (__bf16)gelu_f(acc[mt][nt][r] + bb);
            }
        }
    }
    #pragma unroll
    for (int i = 0; i < 2; i++)
        #pragma unroll
        for (int j = 0; j < 8; j++) acc[i][j] = zero4();
    __syncthreads();   // sB phase-1 reads done + sH2 visible

    // ---- phase 2: h = h2 @ W3^T + b3 + fourier ----
    #pragma unroll
    for (int kb = 0; kb < 4; kb++) {
        if (kb > 0) __syncthreads();
        #pragma unroll
        for (int i = 0; i < 8; i++) {
            int idx = i * 256 + tid;
            int row = idx >> 3, kg = (idx & 7) ^ (row & 7);
            load_lds16(W3 + (size_t)row * 256 + kb * 64 + kg * 8, &sB[idx * 8]);
        }
        __syncthreads();
        #pragma unroll
        for (int ks = 0; ks < 2; ks++) {
            int c = ks * 4 + quad;
            int k0 = kb * 64 + ks * 32 + quad * 8;
            bf16_8 af[2], bfr[8];
            #pragma unroll
            for (int mt = 0; mt < 2; mt++) {
                int mr = wm * 32 + mt * 16 + ln;
                af[mt] = *(const bf16_8*)&sH2[mr * 256 + ((k0 + mr * 8) & 255)];
            }
            #pragma unroll
            for (int nt = 0; nt < 8; nt++) {
                int nr = wn * 128 + nt * 16 + ln;
                bfr[nt] = *(const bf16_8*)&sB[nr * 64 + (c ^ (nr & 7)) * 8];
            }
            #pragma unroll
            for (int mt = 0; mt < 2; mt++)
                #pragma unroll
                for (int nt = 0; nt < 8; nt++)
                    acc[mt][nt] = __builtin_amdgcn_mfma_f32_16x16x32_bf16(af[mt], bfr[nt], acc[mt][nt], 0, 0, 0);
        }
    }
    // epi2: + b3 + fourier -> per-wave transpose (reuse sB) -> 16B in-place stores
    __syncthreads();   // sB phase-2 reads done
    __bf16* buf = sB + wave * 4096;
    float b3r[8], Bc0[8], Bc1[8];
    #pragma unroll
    for (int nt = 0; nt < 8; nt++) {
        int col = wn * 128 + nt * 16 + ln;
        b3r[nt] = b3[col];
        int jm = col & 127;
        Bc0[nt] = bfour[jm * 2 + 0];
        Bc1[nt] = bfour[jm * 2 + 1];
    }
    const bool iscos = (wn == 0);
    #pragma unroll
    for (int mt = 0; mt < 2; mt++) {
        #pragma unroll
        for (int r = 0; r < 4; r++) {
            int rowL = mt * 16 + quad * 4 + r;
            int rowE = m0 + wm * 32 + rowL;
            float p0 = pos[rowE * 2 + 0], p1 = pos[rowE * 2 + 1];
            #pragma unroll
            for (int nt = 0; nt < 8; nt++) {
                float f = 6.2831853071795864f * fmaf(p1, Bc1[nt], p0 * Bc0[nt]);
                float v = acc[mt][nt][r] + b3r[nt] + (iscos ? __cosf(f) : __sinf(f));
                int colL = nt * 16 + ln;
                buf[rowL * 128 + ((colL + rowL * 8) & 127)] = (__bf16)v;
            }
        }
    }
    // wave-private buf: same-wave RAW ordered by lgkmcnt (proven pattern)
    #pragma unroll
    for (int p = 0; p < 8; p++) {
        int rowL = p * 4 + (lane >> 4);
        int c8 = lane & 15;
        bf16_8 vv = *(const bf16_8*)&buf[rowL * 128 + ((c8 * 8 + rowL * 8) & 127)];
        *(bf16_8*)&hA[(size_t)(m0 + wm * 32 + rowL) * 256 + wn * 128 + c8 * 8] = vv;
    }
}

// ---------------- msg_fused: m1=gelu(h[src]@W1a^T+b1+d) ; p2=pool(gelu(m1@W2^T+b2))
// 64 edges/block (4 dst groups). h_src rows resident in LDS; m1 quarter (128
// cols) bounced through LDS; phase-2 accumulates K across quarters. m1 never
// touches global memory. LDS = 32+32+16 = 80 KB -> 2 blocks/CU.
__global__ __launch_bounds__(256, 2) void msg_fused(
    const __bf16* __restrict__ h, const int* __restrict__ edges,
    const __bf16* __restrict__ W1a, const float* __restrict__ b1,
    const __bf16* __restrict__ dmat, const __bf16* __restrict__ W2,
    const float* __restrict__ b2, __bf16* __restrict__ p2)
{
    __shared__ __align__(16) __bf16 sH[64 * 256];    // 32 KB gathered h_src
    __shared__ __align__(16) __bf16 sB[16384];       // 32 KB B slabs (s_src overlay)
    __shared__ __align__(16) __bf16 sM1[64 * 128];   // 16 KB m1 quarter (A-layout)

    const int tid = threadIdx.x;
    const int e0  = blockIdx.x * 64;
    const int wave = tid >> 6, lane = tid & 63, ln = lane & 15, quad = lane >> 4;
    const int wm = wave >> 1, wn = wave & 1;

    int* s_src = (int*)sB;   // overlay: consumed before first sB DMA
    if (tid < 64) s_src[tid] = edges[2 * (e0 + tid) + 1];
    __syncthreads();

    const __bf16* pH[8];
    #pragma unroll
    for (int i = 0; i < 8; i++) {
        int idx = i * 256 + tid;
        int row = idx >> 5, kg = (idx & 31) ^ (row & 7);
        pH[i] = h + (size_t)s_src[row] * 256 + kg * 8;
    }
    __syncthreads();   // all s_src reads done before sB overwrite
    #pragma unroll
    for (int i = 0; i < 8; i++)
        load_lds16(pH[i], &sH[(i * 256 + tid) * 8]);
    // (first phase-1 drain barrier below also drains the gather DMA)

    f32_4 acc2[2][8];
    #pragma unroll
    for (int i = 0; i < 2; i++)
        #pragma unroll
        for (int j = 0; j < 8; j++) acc2[i][j] = zero4();

    #pragma unroll 1
    for (int q = 0; q < 4; q++) {
        // per-quarter bias + d registers (cols colbase..colbase+64 per wave-half)
        const int colbase = q * 128 + wn * 64;
        float b1r[4];
        float dr[2][4];
        #pragma unroll
        for (int nt = 0; nt < 4; nt++) {
            b1r[nt] = b1[colbase + nt * 16 + ln];
            #pragma unroll
            for (int mt = 0; mt < 2; mt++) {
                int gid = blockIdx.x * 4 + wm * 2 + mt;
                dr[mt][nt] = (float)dmat[(size_t)gid * 512 + colbase + nt * 16 + ln];
            }
        }
        f32_4 acc1[2][4];
        #pragma unroll
        for (int i = 0; i < 2; i++)
            #pragma unroll
            for (int j = 0; j < 4; j++) acc1[i][j] = zero4();

        // ---- phase 1: m1 quarter = h_src @ W1a[q*128..+128)^T ----
        #pragma unroll
        for (int kb = 0; kb < 2; kb++) {
            __syncthreads();   // sB free (prev reads done / init gather path)
            #pragma unroll
            for (int i = 0; i < 8; i++) {
                int idx = i * 256 + tid;
                int row = idx >> 4, kg = (idx & 15) ^ (row & 7);
                load_lds16(W1a + (size_t)(q * 128 + row) * 512 + kb * 128 + kg * 8,
                           &sB[idx * 8]);
            }
            __syncthreads();   // drain
            #pragma unroll
            for (int ks = 0; ks < 4; ks++) {
                int ca = kb * 16 + ks * 4 + quad;   // sH chunk 0..31
                int cb = ks * 4 + quad;             // sB chunk 0..15
                bf16_8 af[2], bfr[4];
                #pragma unroll
                for (int mt = 0; mt < 2; mt++) {
                    int mr = wm * 32 + mt * 16 + ln;
                    af[mt] = *(const bf16_8*)&sH[mr * 256 + (ca ^ (mr & 7)) * 8];
                }
                #pragma unroll
                for (int nt = 0; nt < 4; nt++) {
                    int nr = wn * 64 + nt * 16 + ln;
                    bfr[nt] = *(const bf16_8*)&sB[nr * 128 + (cb ^ (nr & 7)) * 8];
                }
                #pragma unroll
                for (int mt = 0; mt < 2; mt++)
                    #pragma unroll
                    for (int nt = 0; nt < 4; nt++)
                        acc1[mt][nt] = __builtin_amdgcn_mfma_f32_16x16x32_bf16(af[mt], bfr[nt], acc1[mt][nt], 0, 0, 0);
            }
        }
        // epi1: gelu(acc1 + b1 + d) -> sM1 (A-layout, add-rotation swizzle)
        #pragma unroll
        for (int mt = 0; mt < 2; mt++) {
            #pragma unroll
            for (int nt = 0; nt < 4; nt++) {
                #pragma unroll
                for (int r = 0; r < 4; r++) {
                    int row = wm * 32 + mt * 16 + quad * 4 + r;
                    int colq = wn * 64 + nt * 16 + ln;
                    float v = gelu_f(acc1[mt][nt][r] + b1r[nt] + dr[mt][nt]);
                    sM1[row * 128 + ((colq + row * 8) & 127)] = (__bf16)v;
                }
            }
        }
        __syncthreads();   // sM1 visible; also sB phase-1 reads done

        // ---- phase 2 partial: acc2 += m1_q @ W2[:, q*128..+128)^T ----
        #pragma unroll
        for (int kb2 = 0; kb2 < 2; kb2++) {
            if (kb2 > 0) __syncthreads();
            #pragma unroll
            for (int i = 0; i < 8; i++) {
                int idx = i * 256 + tid;
                int row = idx >> 3, kg = (idx & 7) ^ (row & 7);
                load_lds16(W2 + (size_t)row * 512 + q * 128 + kb2 * 64 + kg * 8,
                           &sB[idx * 8]);
            }
            __syncthreads();
            #pragma unroll
            for (int ks = 0; ks < 2; ks++) {
                int k0 = kb2 * 64 + ks * 32 + quad * 8;  // within-quarter K
                int cb2 = ks * 4 + quad;                 // sB chunk 0..7
                bf16_8 af[2], bfr[8];
                #pragma unroll
                for (int mt = 0; mt < 2; mt++) {
                    int mr = wm * 32 + mt * 16 + ln;
                    af[mt] = *(const bf16_8*)&sM1[mr * 128 + ((k0 + mr * 8) & 127)];
                }
                #pragma unroll
                for (int nt = 0; nt < 8; nt++) {
                    int nr = wn * 128 + nt * 16 + ln;
                    bfr[nt] = *(const bf16_8*)&sB[nr * 64 + (cb2 ^ (nr & 7)) * 8];
                }
                #pragma unroll
                for (int mt = 0; mt < 2; mt++)
                    #pragma unroll
                    for (int nt = 0; nt < 8; nt++)
                        acc2[mt][nt] = __builtin_amdgcn_mfma_f32_16x16x32_bf16(af[mt], bfr[nt], acc2[mt][nt], 0, 0, 0);
            }
        }
        __syncthreads();   // phase-2 sM1/sB reads done before next quarter reuse
    }

    // pool epilogue: mean of gelu(acc2 + b2) over each 16-row group
    #pragma unroll
    for (int nt = 0; nt < 8; nt++) {
        int col = wn * 128 + nt * 16 + ln;
        float bb = b2[col];
        #pragma unroll
        for (int mt = 0; mt < 2; mt++) {
            float s = gelu_f(acc2[mt][nt][0] + bb) + gelu_f(acc2[mt][nt][1] + bb)
                    + gelu_f(acc2[mt][nt][2] + bb) + gelu_f(acc2[mt][nt][3] + bb);
            s += __shfl_xor(s, 16);
            s += __shfl_xor(s, 32);
            if (quad == 0) {
                int dstn = edges[2 * (e0 + (wm * 2 + mt) * 16)];
                p2[(size_t)dstn * HID + col] = (__bf16)(s * 0.0625f);
            }
        }
    }
}

// ---------------- mgemm (thin 128x128): used for g1d / g3 ----------------
template<int K, int GMODE, int WLD, int WOFF, bool BIAS, bool POOL_, bool F32OUT>
__global__ __launch_bounds__(256, 3) void mgemm(
    const __bf16* __restrict__ Ag, const __bf16* __restrict__ h,
    const int* __restrict__ edges, const __bf16* __restrict__ W,
    const float* __restrict__ bias, __bf16* __restrict__ Cb,
    float* __restrict__ Cf, int NB, int Nfull, int e0)
{
    __shared__ __align__(16) __bf16 sA[128 * 64];
    __shared__ __align__(16) __bf16 sB[128 * 64];
    __shared__ int s_idx[128];

    const int tid  = threadIdx.x;
    const int mblk = blockIdx.x / NB;
    const int nblk = blockIdx.x % NB;
    const int m0 = mblk * 128, n0 = nblk * 128;
    const int wave = tid >> 6, lane = tid & 63, ln = lane & 15, quad = lane >> 4;
    const int wm = wave >> 1, wn = wave & 1;

    if (GMODE) {
        if (tid < 128) {
            int r = m0 + tid;
            s_idx[tid] = (GMODE == 1) ? edges[2 * (e0 + r) + 1]
                                      : edges[2 * (DEG * r)];
        }
        __syncthreads();
    }

    const __bf16* pA[4];
    const __bf16* pB[4];
    #pragma unroll
    for (int i = 0; i < 4; i++) {
        int idx = i * 256 + tid;
        int row = idx >> 3, kg = (idx & 7) ^ (row & 7);
        pA[i] = GMODE ? h + (size_t)s_idx[row] * HID + kg * 8
                      : Ag + (size_t)(m0 + row) * K + kg * 8;
        pB[i] = W + (size_t)(n0 + row) * WLD + WOFF + kg * 8;
    }
    const int ach = quad ^ (ln & 7);
    const int aof[2] = { (wm * 64 + ln) * 64 + ach * 8, (wm * 64 + ln) * 64 + (ach ^ 4) * 8 };
    const int bof[2] = { (wn * 64 + ln) * 64 + ach * 8, (wn * 64 + ln) * 64 + (ach ^ 4) * 8 };

    f32_4 acc[4][4];
    #pragma unroll
    for (int i = 0; i < 4; i++)
        #pragma unroll
        for (int j = 0; j < 4; j++) acc[i][j] = zero4();

    bf16_8 ar[4], br[4];
    #pragma unroll
    for (int i = 0; i < 4; i++) {
        ar[i] = *(const bf16_8*)pA[i];
        br[i] = *(const bf16_8*)pB[i];
    }

    #pragma unroll
    for (int kb = 0; kb < K / 64; kb++) {
        if (kb > 0) __syncthreads();
        #pragma unroll
        for (int i = 0; i < 4; i++) {
            int idx = i * 256 + tid;
            *(bf16_8*)&sA[idx * 8] = ar[i];
            *(bf16_8*)&sB[idx * 8] = br[i];
        }
        __syncthreads();
        if (kb + 1 < K / 64) {
            #pragma unroll
            for (int i = 0; i < 4; i++) {
                ar[i] = *(const bf16_8*)(pA[i] + (kb + 1) * 64);
                br[i] = *(const bf16_8*)(pB[i] + (kb + 1) * 64);
            }
        }
        #pragma unroll
        for (int ks = 0; ks < 2; ks++) {
            bf16_8 af[4], bfr[4];
            #pragma unroll
            for (int mt = 0; mt < 4; mt++) af[mt]  = *(const bf16_8*)&sA[aof[ks] + mt * 1024];
            #pragma unroll
            for (int nt = 0; nt < 4; nt++) bfr[nt] = *(const bf16_8*)&sB[bof[ks] + nt * 1024];
            #pragma unroll
            for (int mt = 0; mt < 4; mt++)
                #pragma unroll
                for (int nt = 0; nt < 4; nt++)
                    acc[mt][nt] = __builtin_amdgcn_mfma_f32_16x16x32_bf16(af[mt], bfr[nt], acc[mt][nt], 0, 0, 0);
        }
    }

    if (POOL_) {
        #pragma unroll
        for (int nt = 0; nt < 4; nt++) {
            int col = n0 + wn * 64 + nt * 16 + ln;
            float bb = BIAS ? bias[col] : 0.f;
            #pragma unroll
            for (int mt = 0; mt < 4; mt++) {
                float s = gelu_f(acc[mt][nt][0] + bb) + gelu_f(acc[mt][nt][1] + bb)
                        + gelu_f(acc[mt][nt][2] + bb) + gelu_f(acc[mt][nt][3] + bb);
                s += __shfl_xor(s, 16);
                s += __shfl_xor(s, 32);
                if (quad == 0) {
                    int eg  = e0 + m0 + wm * 64 + mt * 16;
                    int dstn = edges[2 * eg];
                    Cb[(size_t)dstn * HID + col] = (__bf16)(s * 0.0625f);
                }
            }
        }
    } else if (F32OUT) {
        #pragma unroll
        for (int nt = 0; nt < 4; nt++) {
            int col = n0 + wn * 64 + nt * 16 + ln;
            float bb = BIAS ? bias[col] : 0.f;
            #pragma unroll
            for (int mt = 0; mt < 4; mt++) {
                #pragma unroll
                for (int r = 0; r < 4; r++) {
                    int rowE = m0 + wm * 64 + mt * 16 + quad * 4 + r;
                    Cf[(size_t)rowE * Nfull + col] = acc[mt][nt][r] + bb;
                }
            }
        }
    } else {
        // raw bf16 transpose-store (g1d)
        __syncthreads();
        __bf16* sw = ((wave & 2) ? sB : sA) + (wave & 1) * 4096;
        #pragma unroll
        for (int nt = 0; nt < 4; nt++) {
            #pragma unroll
            for (int mt = 0; mt < 4; mt++) {
                #pragma unroll
                for (int r = 0; r < 4; r++) {
                    int rowL = mt * 16 + quad * 4 + r;
                    int colL = nt * 16 + ln;
                    sw[rowL * 64 + ((colL + rowL * 8) & 63)] = (__bf16)acc[mt][nt][r];
                }
            }
        }
        __syncthreads();
        #pragma unroll
        for (int p = 0; p < 8; p++) {
            int rowL = p * 8 + (lane >> 3);
            int c8 = lane & 7;
            bf16_8 vv = *(const bf16_8*)&sw[rowL * 64 + ((c8 * 8 + rowL * 8) & 63)];
            int rowE = m0 + wm * 64 + rowL;
            *(bf16_8*)&Cb[(size_t)rowE * Nfull + n0 + wn * 64 + c8 * 8] = vv;
        }
    }
}

extern "C" void kernel_launch(void* const* d_in, const int* in_sizes, int n_in,
                              void* d_out, int out_size, void* d_ws, size_t ws_size,
                              hipStream_t stream) {
    const float* x     = (const float*)d_in[0];
    const float* pos   = (const float*)d_in[1];
    const int*   edges = (const int*)d_in[2];
    const float* ip_w1 = (const float*)d_in[4];
    const float* ip_b1 = (const float*)d_in[5];
    const float* ip_w2 = (const float*)d_in[6];
    const float* ip_b2 = (const float*)d_in[7];
    const float* ip_w3 = (const float*)d_in[8];
    const float* ip_b3 = (const float*)d_in[9];
    const float* bfour = (const float*)d_in[10];
    const float* mw1   = (const float*)d_in[11];
    const float* mb1   = (const float*)d_in[12];
    const float* mw2   = (const float*)d_in[13];
    const float* mb2   = (const float*)d_in[14];
    const float* mw3   = (const float*)d_in[15];
    const float* mb3   = (const float*)d_in[16];

    // workspace: hA 64 MB | weights 1.125 MB | dbuf 16 MB | p2 8 MB  (~89 MB)
    char* ws = (char*)d_ws;
    __bf16* hA = (__bf16*)ws;
    size_t off = (size_t)N_NODES * HID * 2;
    __bf16* wb = (__bf16*)(ws + off);
    off += (size_t)589824 * 2;
    off = (off + 255) & ~(size_t)255;
    __bf16* dbuf = (__bf16*)(ws + off);                      // d = h_dst @ W1b^T
    off += (size_t)N_DST * 512 * 2;
    __bf16* p2 = (__bf16*)(ws + off);                        // pooled m2
    off += (size_t)N_DST * HID * 2;

    __bf16* w2b  = wb;
    __bf16* w3b  = wb + 65536;
    __bf16* mw1b = wb + 131072;
    __bf16* mw2b = wb + 393216;
    __bf16* mw3b = wb + 524288;

    prep_kernel<<<2304, 256, 0, stream>>>(wb, ip_w2, ip_w3, mw1, mw2, mw3);

    // encoder: h1 -> hA; fused L2+L3 (+fourier) in-place on hA
    enc1_kernel<<<2048, 256, 0, stream>>>(x, ip_w1, ip_b1, hA);
    enc23_kernel<<<2048, 256, 0, stream>>>(hA, w2b, ip_b2, w3b, ip_b3, pos, bfour);

    // d[g] = h[dst(g)] @ W1b^T  (16384 x 512, K=256)
    mgemm<256, 2, 512, 256, false, false, false><<<512, 256, 0, stream>>>(
        nullptr, hA, edges, mw1b, nullptr, dbuf, nullptr, 4, 512, 0);

    // fused message MLP + pool: p2[dst] = mean(gelu(gelu(h_src@W1a^T+b1+d)@W2^T+b2))
    msg_fused<<<4096, 256, 0, stream>>>(hA, edges, mw1b, mb1, dbuf, mw2b, mb2, p2);

    // out = p2 @ W3^T + b3  (16384 x 256, K=256), fp32
    mgemm<256, 0, 256, 0, true, false, true><<<256, 256, 0, stream>>>(
        p2, nullptr, nullptr, mw3b, mb3, nullptr, (float*)d_out, 2, 256, 0);
}